// Round 10
// baseline (343.395 us; speedup 1.0000x reference)
//
#include <hip/hip_runtime.h>
#include <hip/hip_cooperative_groups.h>
#include <math.h>

namespace cg = cooperative_groups;

// Problem constants (from reference)
#define NCH 129
#define BS 8
#define TLEN 64000
#define HALF 128          // state granularity AND kC tile length
#define NH 500            // TLEN / HALF
#define LFRM 256          // frame stride
#define NFRM 250          // number of frames
#define NSEQ (NCH * BS)   // 1032 sequences
#define NBK (BS * NFRM)   // 2000 (b,frame) cells
#define NT (BS * NH)      // 4000 (b,tile) cells
#define KC_EDGE 16        // ceil(NT/256): phase-C channel-128 virtual blocks
#define KC_MAIN (NT / 4)  // 1000 main virtual blocks (4 tiles per 256-thr block)
#define KC_TOT (KC_EDGE + KC_MAIN)
#define KA_EDGE 63        // ceil(NT/64) fallback kA edge blocks
#define MAXGRID 1024

typedef float f2 __attribute__((ext_vector_type(2)));

__device__ __forceinline__ f2 mk2(float a, float b) { f2 r; r.x = a; r.y = b; return r; }

__device__ __forceinline__ f2 fma2(f2 a, f2 b, f2 c) {
#if __has_builtin(__builtin_elementwise_fma)
    return __builtin_elementwise_fma(a, b, c);
#else
    f2 r; r.x = fmaf(a.x, b.x, c.x); r.y = fmaf(a.y, b.y, c.y); return r;
#endif
}

__device__ __forceinline__ f2 sig2(f2 v) {
    f2 r;
    r.x = __builtin_amdgcn_rcpf(1.0f + __expf(-v.x));
    r.y = __builtin_amdgcn_rcpf(1.0f + __expf(-v.y));
    return r;
}

// Packed pair-of-chains coefficients.
struct C2 { f2 b0, b1, b2, b3, b4, a1, a2, a3, a4; };

__device__ __forceinline__ C2 load_coef2(const float* __restrict__ B,
                                         const float* __restrict__ A,
                                         int cx, int cy) {
    C2 q;
    q.b0 = mk2(B[cx * 5 + 0], B[cy * 5 + 0]);
    q.b1 = mk2(B[cx * 5 + 1], B[cy * 5 + 1]);
    q.b2 = mk2(B[cx * 5 + 2], B[cy * 5 + 2]);
    q.b3 = mk2(B[cx * 5 + 3], B[cy * 5 + 3]);
    q.b4 = mk2(B[cx * 5 + 4], B[cy * 5 + 4]);
    q.a1 = mk2(A[cx * 5 + 1], A[cy * 5 + 1]);
    q.a2 = mk2(A[cx * 5 + 2], A[cy * 5 + 2]);
    q.a3 = mk2(A[cx * 5 + 3], A[cy * 5 + 3]);
    q.a4 = mk2(A[cx * 5 + 4], A[cy * 5 + 4]);
    return q;
}

__device__ __forceinline__ f2 iir2_step(const C2& q, float x,
                                        f2& z0, f2& z1, f2& z2, f2& z3) {
    f2 xx = mk2(x, x);
    f2 y = fma2(q.b0, xx, z0);
    z0 = fma2(-q.a1, y, fma2(q.b1, xx, z1));
    z1 = fma2(-q.a2, y, fma2(q.b2, xx, z2));
    z2 = fma2(-q.a3, y, fma2(q.b3, xx, z3));
    z3 = fma2(-q.a4, y, q.b4 * xx);
    return y;
}

// Scalar variants (channel-128 forced-state only).
struct Coef { float b0, b1, b2, b3, b4, a1, a2, a3, a4; };
__device__ __forceinline__ Coef load_coef(const float* __restrict__ B,
                                          const float* __restrict__ A, int c) {
    Coef q;
    q.b0 = B[c * 5 + 0]; q.b1 = B[c * 5 + 1]; q.b2 = B[c * 5 + 2];
    q.b3 = B[c * 5 + 3]; q.b4 = B[c * 5 + 4];
    q.a1 = A[c * 5 + 1]; q.a2 = A[c * 5 + 2];
    q.a3 = A[c * 5 + 3]; q.a4 = A[c * 5 + 4];
    return q;
}
__device__ __forceinline__ float iir_step(const Coef& q, float x,
                                          float& z0, float& z1, float& z2, float& z3) {
    float y = fmaf(q.b0, x, z0);
    z0 = fmaf(-q.a1, y, fmaf(q.b1, x, z1));
    z1 = fmaf(-q.a2, y, fmaf(q.b2, x, z2));
    z2 = fmaf(-q.a3, y, fmaf(q.b3, x, z3));
    z3 = fmaf(-q.a4, y, q.b4 * x);
    return y;
}

// step macros for packed chains
#define ISTEP(xv) { (void)iir2_step(q, (xv), z0, z1, z2, z3); }
#define WSTEP(xv)                                                              \
    { f2 y_ = iir2_step(q, (xv), z0, z1, z2, z3);                              \
      u = fma2(beta2, u, sig2(y_)); }
#define MSTEP(xv)                                                              \
    { f2 y_ = iir2_step(q, (xv), z0, z1, z2, z3);                              \
      u = fma2(beta2, u, sig2(y_));                                            \
      float un_ = __shfl_down(u.x, 1, 64);                                     \
      float y4o_ = fmaxf(u.y - u.x, 0.0f);                                     \
      float y4e_ = fmaxf(pend_un - pend_ub, 0.0f);                             \
      g2 = fma2(alpha2, g2, mk2(y4o_, y4e_));                                  \
      pend_un = un_; pend_ub = u.y; }

// ---- 4x4 matrix helpers over 16 NAMED scalars (no arrays -> no scratch) ----
#define MDECL(X) float X##00, X##01, X##02, X##03, X##10, X##11, X##12, X##13, \
                       X##20, X##21, X##22, X##23, X##30, X##31, X##32, X##33
#define MCOPY(D, S) D##00=S##00; D##01=S##01; D##02=S##02; D##03=S##03;        \
                    D##10=S##10; D##11=S##11; D##12=S##12; D##13=S##13;        \
                    D##20=S##20; D##21=S##21; D##22=S##22; D##23=S##23;        \
                    D##30=S##30; D##31=S##31; D##32=S##32; D##33=S##33
#define MROW(R, X, Y, i)                                                       \
    R##i##0 = fmaf(X##i##0, Y##00, fmaf(X##i##1, Y##10, fmaf(X##i##2, Y##20, X##i##3 * Y##30))); \
    R##i##1 = fmaf(X##i##0, Y##01, fmaf(X##i##1, Y##11, fmaf(X##i##2, Y##21, X##i##3 * Y##31))); \
    R##i##2 = fmaf(X##i##0, Y##02, fmaf(X##i##1, Y##12, fmaf(X##i##2, Y##22, X##i##3 * Y##32))); \
    R##i##3 = fmaf(X##i##0, Y##03, fmaf(X##i##1, Y##13, fmaf(X##i##2, Y##23, X##i##3 * Y##33)))
#define MMUL(R, X, Y) MROW(R, X, Y, 0); MROW(R, X, Y, 1); MROW(R, X, Y, 2); MROW(R, X, Y, 3)
#define MV(r, X, v)                                                            \
    r.x = fmaf(X##00, v.x, fmaf(X##01, v.y, fmaf(X##02, v.z, X##03 * v.w)));   \
    r.y = fmaf(X##10, v.x, fmaf(X##11, v.y, fmaf(X##12, v.z, X##13 * v.w)));   \
    r.z = fmaf(X##20, v.x, fmaf(X##21, v.y, fmaf(X##22, v.z, X##23 * v.w)));   \
    r.w = fmaf(X##30, v.x, fmaf(X##31, v.y, fmaf(X##32, v.z, X##33 * v.w)))

// phase-B macros
#define KB_LOAD(dn, i)                                                         \
    {   int hh = h0 + (i); int hcl = (hh < NH) ? hh : (NH - 1);                \
        dn = zb[(size_t)hcl * NSEQ + id];                                      \
        if (hh >= NH) dn = make_float4(0.f, 0.f, 0.f, 0.f); }
#define KB_FOLD(dn)                                                            \
    {   float4 t_; MV(t_, M1, e);                                              \
        e.x = t_.x + dn.x; e.y = t_.y + dn.y;                                  \
        e.z = t_.z + dn.z; e.w = t_.w + dn.w; }
#define KB_REPLAY(dn, i)                                                       \
    {   int hh = h0 + (i);                                                     \
        if (hh < NH) zbw[(size_t)hh * NSEQ + id] = zz;                         \
        float4 t_; MV(t_, M1, zz);                                             \
        zz.x = t_.x + dn.x; zz.y = t_.y + dn.y;                                \
        zz.z = t_.z + dn.z; zz.w = t_.w + dn.w; }

// phase-D macros
#define KD_LOAD(gn, yn, i)                                                     \
    {   int kk = k0 + (i); int kcl = (kk < NFRM) ? kk : (NFRM - 1);            \
        size_t ix = ((size_t)b * NFRM + kcl) * NCH + c;                        \
        gn = fmaf(aH, G1[ix], G2[ix]); yn = y4f[ix];                           \
        if (kk >= NFRM) { gn = 0.f; yn = 0.f; } }
#define KD_REPLAY(gn, yn, i)                                                   \
    {   int kk = k0 + (i);                                                     \
        if (kk < NFRM) o[kk] = fmaf(alpha, sv, yn);                            \
        sv = fmaf(aL, sv, gn); }

// ===========================================================================
// Device-side phase bodies (shared by mega + fallback kernels)
// ===========================================================================

// ---- phase A main: one wave per tile, packed channels {2t,2t+1} ----
__device__ __forceinline__ void phaseA_tile(
        const float* __restrict__ wav, const float* __restrict__ B,
        const float* __restrict__ A, float* __restrict__ zs,
        int tile, int lane) {
    int b = tile / NH;
    int h = tile - b * NH;
    const float4* xv = (const float4*)(wav + (size_t)b * TLEN + (size_t)h * HALF);
    C2 q = load_coef2(B, A, 2 * lane, 2 * lane + 1);
    f2 z0 = mk2(0.f, 0.f), z1 = z0, z2 = z0, z3 = z0;
    #pragma unroll 2
    for (int g = 0; g < HALF / 4; ++g) {
        float4 xq = xv[g];
        ISTEP(xq.x); ISTEP(xq.y); ISTEP(xq.z); ISTEP(xq.w);
    }
    size_t base = (size_t)h * NSEQ;
    ((float4*)zs)[base + (2 * lane) * BS + b]     = make_float4(z0.x, z1.x, z2.x, z3.x);
    ((float4*)zs)[base + (2 * lane + 1) * BS + b] = make_float4(z0.y, z1.y, z2.y, z3.y);
}

// ---- phase A edge: channel 128, one (b,h) cell per thread ----
__device__ __forceinline__ void phaseA_edge(
        const float* __restrict__ wav, const float* __restrict__ B,
        const float* __restrict__ A, float* __restrict__ zs, int cell) {
    int b = cell / NH;
    int h = cell - b * NH;
    const float4* xv = (const float4*)(wav + (size_t)b * TLEN + (size_t)h * HALF);
    Coef qe = load_coef(B, A, 128);
    float z0 = 0.f, z1 = 0.f, z2 = 0.f, z3 = 0.f;
    #pragma unroll 2
    for (int g = 0; g < HALF / 4; ++g) {
        float4 xq = xv[g];
        (void)iir_step(qe, xq.x, z0, z1, z2, z3);
        (void)iir_step(qe, xq.y, z0, z1, z2, z3);
        (void)iir_step(qe, xq.z, z0, z1, z2, z3);
        (void)iir_step(qe, xq.w, z0, z1, z2, z3);
    }
    ((float4*)zs)[(size_t)h * NSEQ + 128 * BS + b] = make_float4(z0, z1, z2, z3);
}

// ---- phase B: matrix Kogge-Stone scan for one sequence (one wave) ----
__device__ __forceinline__ void phaseB_seq(
        const float* __restrict__ A, float* __restrict__ zs, int id, int lane) {
    int c = id / BS;
    float a1 = A[c * 5 + 1], a2 = A[c * 5 + 2], a3 = A[c * 5 + 3], a4 = A[c * 5 + 4];
    MDECL(M1);
    M100 = -a1; M101 = 1.f; M102 = 0.f; M103 = 0.f;
    M110 = -a2; M111 = 0.f; M112 = 1.f; M113 = 0.f;
    M120 = -a3; M121 = 0.f; M122 = 0.f; M123 = 1.f;
    M130 = -a4; M131 = 0.f; M132 = 0.f; M133 = 0.f;
    for (int s = 0; s < 7; ++s) {        // M^128
        MDECL(T); MMUL(T, M1, M1); MCOPY(M1, T);
    }
    MDECL(P);
    MCOPY(P, M1);
    for (int s = 0; s < 3; ++s) {        // P = M128^8
        MDECL(T); MMUL(T, P, P); MCOPY(P, T);
    }
    const float4* zb = (const float4*)zs;
    float4* zbw = (float4*)zs;
    int h0 = lane * 8;
    float4 d0, d1, d2, d3, d4, d5, d6, d7;
    KB_LOAD(d0, 0); KB_LOAD(d1, 1); KB_LOAD(d2, 2); KB_LOAD(d3, 3);
    KB_LOAD(d4, 4); KB_LOAD(d5, 5); KB_LOAD(d6, 6); KB_LOAD(d7, 7);
    float4 e = d0;
    KB_FOLD(d1); KB_FOLD(d2); KB_FOLD(d3); KB_FOLD(d4);
    KB_FOLD(d5); KB_FOLD(d6); KB_FOLD(d7);
    for (int s = 0; s < 6; ++s) {
        int off = 1 << s;
        float4 src;
        src.x = __shfl_up(e.x, off, 64);
        src.y = __shfl_up(e.y, off, 64);
        src.z = __shfl_up(e.z, off, 64);
        src.w = __shfl_up(e.w, off, 64);
        if (lane < off) { src.x = 0.f; src.y = 0.f; src.z = 0.f; src.w = 0.f; }
        float4 t_; MV(t_, P, src);
        e.x += t_.x; e.y += t_.y; e.z += t_.z; e.w += t_.w;
        if (s < 5) { MDECL(T); MMUL(T, P, P); MCOPY(P, T); }
    }
    float4 zz;
    zz.x = __shfl_up(e.x, 1, 64);
    zz.y = __shfl_up(e.y, 1, 64);
    zz.z = __shfl_up(e.z, 1, 64);
    zz.w = __shfl_up(e.w, 1, 64);
    if (lane == 0) { zz.x = 0.f; zz.y = 0.f; zz.z = 0.f; zz.w = 0.f; }
    KB_REPLAY(d0, 0); KB_REPLAY(d1, 1); KB_REPLAY(d2, 2); KB_REPLAY(d3, 3);
    KB_REPLAY(d4, 4); KB_REPLAY(d5, 5); KB_REPLAY(d6, 6); KB_REPLAY(d7, 7);
}

// ---- phase C edge: channel 128, one (b,r) cell per thread ----
__device__ __forceinline__ void phaseC_edge(
        const float* __restrict__ wav, const float* __restrict__ B,
        const float* __restrict__ A, const float* __restrict__ zs,
        float* __restrict__ G1, float* __restrict__ G2,
        float* __restrict__ y4f, float beta, float alpha, int cell) {
    const f2 beta2 = mk2(beta, beta);
    int b = cell / NH;
    int r = cell - b * NH;
    int k = r >> 1, half = r & 1;
    C2 q = load_coef2(B, A, 127, 128);
    f2 z0 = mk2(0.f, 0.f), z1 = z0, z2 = z0, z3 = z0, u = z0;
    const float* xg;
    if (r > 0) {
        float4 vx = ((const float4*)zs)[(size_t)(r - 1) * NSEQ + (127 * BS + b)];
        float4 vy = ((const float4*)zs)[(size_t)(r - 1) * NSEQ + (128 * BS + b)];
        z0 = mk2(vx.x, vy.x); z1 = mk2(vx.y, vy.y);
        z2 = mk2(vx.z, vy.z); z3 = mk2(vx.w, vy.w);
        xg = wav + (size_t)b * TLEN + (size_t)(r - 1) * HALF;
        #pragma unroll 2
        for (int j = 0; j < HALF / 2; ++j) ISTEP(xg[j]);
        #pragma unroll 2
        for (int j = HALF / 2; j < HALF; ++j) WSTEP(xg[j]);
        xg += HALF;
    } else {
        xg = wav + (size_t)b * TLEN;
    }
    float g4 = 0.f, yfirst = 0.f;
    #pragma unroll 2
    for (int j = 0; j < HALF; ++j) {
        f2 y_ = iir2_step(q, xg[j], z0, z1, z2, z3);
        u = fma2(beta2, u, sig2(y_));
        float y4 = fmaxf(u.y - u.x, 0.0f);   // ch128 - ch127
        if (j == 0) yfirst = y4;
        g4 = fmaf(alpha, g4, y4);
    }
    size_t idx = ((size_t)b * NFRM + k) * NCH + 128;
    if (half == 0) { G1[idx] = g4; y4f[idx] = yfirst; }
    else           { G2[idx] = g4; }
}

// ---- phase C main: one wave per tile; seg = this wave's 64-float4 LDS ----
__device__ __forceinline__ void phaseC_tile(
        const float* __restrict__ B, const float* __restrict__ A,
        const float* __restrict__ zs, float* __restrict__ G1,
        float* __restrict__ G2, float* __restrict__ y4f,
        float beta, float alpha, int tile, int lane, const float4* seg) {
    const f2 beta2 = mk2(beta, beta);
    const f2 alpha2 = mk2(alpha, alpha);
    int b = tile / NH;
    int r = tile - b * NH;
    int k = r >> 1, half = r & 1;
    int t = lane;
    int cA = 2 * t, cB2 = 2 * t + 1;
    C2 q = load_coef2(B, A, cA, cB2);
    f2 z0 = mk2(0.f, 0.f), z1 = z0, z2 = z0, z3 = z0, u = z0;
    int gbase = 0;
    if (r > 0) {
        float4 vx = ((const float4*)zs)[(size_t)(r - 1) * NSEQ + (cA * BS + b)];
        float4 vy = ((const float4*)zs)[(size_t)(r - 1) * NSEQ + (cB2 * BS + b)];
        z0 = mk2(vx.x, vy.x); z1 = mk2(vx.y, vy.y);
        z2 = mk2(vx.z, vy.z); z3 = mk2(vx.w, vy.w);
        for (int g = 0; g < HALF / 8; ++g) {        // 64 steps IIR-only
            float4 xq = seg[g];
            ISTEP(xq.x); ISTEP(xq.y); ISTEP(xq.z); ISTEP(xq.w);
        }
        for (int g = HALF / 8; g < HALF / 4; ++g) { // 64 full warm
            float4 xq = seg[g];
            WSTEP(xq.x); WSTEP(xq.y); WSTEP(xq.z); WSTEP(xq.w);
        }
        gbase = HALF / 4;
    }
    f2 g2;
    float fo, fe, pend_un, pend_ub;
    {   // first group: peel j=0 and j=1
        float4 xq = seg[gbase];
        f2 y_ = iir2_step(q, xq.x, z0, z1, z2, z3);
        u = fma2(beta2, u, sig2(y_));
        float un_ = __shfl_down(u.x, 1, 64);
        float y4o_ = fmaxf(u.y - u.x, 0.0f);
        fo = y4o_;
        g2 = mk2(y4o_, 0.0f);
        pend_un = un_; pend_ub = u.y;
        y_ = iir2_step(q, xq.y, z0, z1, z2, z3);
        u = fma2(beta2, u, sig2(y_));
        un_ = __shfl_down(u.x, 1, 64);
        y4o_ = fmaxf(u.y - u.x, 0.0f);
        float y4e_ = fmaxf(pend_un - pend_ub, 0.0f);
        fe = y4e_;
        g2 = fma2(alpha2, g2, mk2(y4o_, y4e_));
        pend_un = un_; pend_ub = u.y;
        MSTEP(xq.z); MSTEP(xq.w);
    }
    for (int g = gbase + 1; g < gbase + HALF / 4; ++g) {
        float4 xq = seg[g];
        MSTEP(xq.x); MSTEP(xq.y); MSTEP(xq.z); MSTEP(xq.w);
    }
    float y4e_last = fmaxf(pend_un - pend_ub, 0.0f);
    float go = g2.x;
    float ge = fmaf(alpha, g2.y, y4e_last);
    size_t base = ((size_t)b * NFRM + k) * NCH;
    if (half == 0) {
        G1[base + cB2] = go;
        y4f[base + cB2] = fo;
        if (t < 63) {
            G1[base + cB2 + 1] = ge;
            y4f[base + cB2 + 1] = fe;
        }
    } else {
        G2[base + cB2] = go;
        if (t < 63) G2[base + cB2 + 1] = ge;
    }
}

// ---- phase D: scalar Kogge-Stone alpha scan for one sequence (one wave) ----
__device__ __forceinline__ void phaseD_seq(
        const float* __restrict__ G1, const float* __restrict__ G2,
        const float* __restrict__ y4f, float* __restrict__ out,
        float alpha, float aL, float aH, int id, int lane) {
    int b = id / NCH;
    int c = id - b * NCH;
    float* o = out + (size_t)id * NFRM;
    int k0 = lane * 4;
    if (c == 0) {
        #pragma unroll
        for (int i = 0; i < 4; ++i) {
            int kk = k0 + i;
            if (kk < NFRM) o[kk] = 0.0f;
        }
        return;
    }
    float g0, g1, g2v, g3, y0, y1, y2v, y3;
    KD_LOAD(g0, y0, 0); KD_LOAD(g1, y1, 1); KD_LOAD(g2v, y2v, 2); KD_LOAD(g3, y3, 3);
    float e = g0;
    e = fmaf(aL, e, g1);
    e = fmaf(aL, e, g2v);
    e = fmaf(aL, e, g3);
    float aL2 = aL * aL;
    float f = aL2 * aL2;                 // aL^4
    for (int s = 0; s < 6; ++s) {
        int off = 1 << s;
        float src = __shfl_up(e, off, 64);
        if (lane < off) src = 0.f;
        e = fmaf(f, src, e);
        f = f * f;
    }
    float sv = __shfl_up(e, 1, 64);
    if (lane == 0) sv = 0.f;
    KD_REPLAY(g0, y0, 0); KD_REPLAY(g1, y1, 1);
    KD_REPLAY(g2v, y2v, 2); KD_REPLAY(g3, y3, 3);
}

// ===========================================================================
// Mega kernel (cooperative): all four phases, grid-stride, 3 grid syncs.
// ===========================================================================
__global__ __launch_bounds__(256, 4) void mega(
        const float* __restrict__ wav, const float* __restrict__ B,
        const float* __restrict__ A, float* __restrict__ zs,
        float* __restrict__ G1, float* __restrict__ G2,
        float* __restrict__ y4f, float* __restrict__ out,
        float alpha, float beta, float aL, float aH) {
    cg::grid_group grid = cg::this_grid();
    __shared__ float4 xs4[4 * 64];
    int wave = threadIdx.x >> 6;
    int lane = threadIdx.x & 63;
    int nblk = gridDim.x;

    // Phase A
    for (int tile = blockIdx.x * 4 + wave; tile < NT; tile += nblk * 4)
        phaseA_tile(wav, B, A, zs, tile, lane);
    for (int cell = blockIdx.x * 256 + threadIdx.x; cell < NT; cell += nblk * 256)
        phaseA_edge(wav, B, A, zs, cell);
    grid.sync();

    // Phase B
    for (int id = blockIdx.x * 4 + wave; id < NSEQ; id += nblk * 4)
        phaseB_seq(A, zs, id, lane);
    grid.sync();

    // Phase C (virtual blocks; __syncthreads fencing for LDS reuse)
    for (int vb = blockIdx.x; vb < KC_TOT; vb += nblk) {
        if (vb < KC_EDGE) {
            int cell = vb * 256 + threadIdx.x;
            if (cell < NT)
                phaseC_edge(wav, B, A, zs, G1, G2, y4f, beta, alpha, cell);
        } else {
            int tile = (vb - KC_EDGE) * 4 + wave;   // < NT by construction
            int b = tile / NH;
            int r = tile - b * NH;
            int n4 = (r > 0) ? 64 : 32;
            const float* xg = wav + (size_t)b * TLEN +
                              ((r > 0) ? (size_t)(r - 1) * HALF : (size_t)0);
            float4* seg = xs4 + wave * 64;
            if (lane < n4) seg[lane] = ((const float4*)xg)[lane];
            __syncthreads();
            phaseC_tile(B, A, zs, G1, G2, y4f, beta, alpha, tile, lane, seg);
            __syncthreads();
        }
    }
    grid.sync();

    // Phase D
    for (int id = blockIdx.x * 4 + wave; id < NSEQ; id += nblk * 4)
        phaseD_seq(G1, G2, y4f, out, alpha, aL, aH, id, lane);
}

// ===========================================================================
// Fallback kernels (round-8 proven path)
// ===========================================================================
__global__ __launch_bounds__(128, 4) void kA_forced_state(
        const float* __restrict__ wav, const float* __restrict__ B,
        const float* __restrict__ A, float* __restrict__ zs) {
    int blk = blockIdx.x;
    int wave = threadIdx.x >> 6;
    int lane = threadIdx.x & 63;
    if (blk < KA_EDGE) {
        if (wave == 0) {
            int cell = blk * 64 + lane;
            if (cell < NT) phaseA_edge(wav, B, A, zs, cell);
        }
        return;
    }
    int tile2 = (blk - KA_EDGE) * 2 + wave;   // 2 tiles per 128-thr block
    if (tile2 < NT) phaseA_tile(wav, B, A, zs, tile2, lane);
}

__global__ __launch_bounds__(256) void kB_scan_par(
        const float* __restrict__ A, float* __restrict__ zs) {
    int id = blockIdx.x * 4 + (threadIdx.x >> 6);
    int lane = threadIdx.x & 63;
    if (id < NSEQ) phaseB_seq(A, zs, id, lane);
}

__global__ __launch_bounds__(256, 8) void kC_main(
        const float* __restrict__ wav, const float* __restrict__ B,
        const float* __restrict__ A, const float* __restrict__ zs,
        float* __restrict__ G1, float* __restrict__ G2,
        float* __restrict__ y4f, float beta, float alpha) {
    __shared__ float4 xs4[4 * 64];
    int blk = blockIdx.x;
    int wave = threadIdx.x >> 6;
    int lane = threadIdx.x & 63;
    if (blk < KC_EDGE) {
        int cell = blk * 256 + threadIdx.x;
        if (cell < NT)
            phaseC_edge(wav, B, A, zs, G1, G2, y4f, beta, alpha, cell);
        return;
    }
    int tile = (blk - KC_EDGE) * 4 + wave;
    int b = tile / NH;
    int r = tile - b * NH;
    int n4 = (r > 0) ? 64 : 32;
    const float* xg = wav + (size_t)b * TLEN +
                      ((r > 0) ? (size_t)(r - 1) * HALF : (size_t)0);
    float4* seg = xs4 + wave * 64;
    if (lane < n4) seg[lane] = ((const float4*)xg)[lane];
    __syncthreads();
    phaseC_tile(B, A, zs, G1, G2, y4f, beta, alpha, tile, lane, seg);
}

__global__ __launch_bounds__(256) void kD_scan_par(
        const float* __restrict__ G1, const float* __restrict__ G2,
        const float* __restrict__ y4f, float* __restrict__ out,
        float alpha, float aL, float aH) {
    int id = blockIdx.x * 4 + (threadIdx.x >> 6);
    int lane = threadIdx.x & 63;
    if (id < NSEQ) phaseD_seq(G1, G2, y4f, out, alpha, aL, aH, id, lane);
}

// ---------------------------------------------------------------------------
extern "C" void kernel_launch(void* const* d_in, const int* in_sizes, int n_in,
                              void* d_out, int out_size, void* d_ws, size_t ws_size,
                              hipStream_t stream) {
    const float* wav = (const float*)d_in[0];   // (BS, TLEN)
    const float* Bc  = (const float*)d_in[1];   // (NCH, 5)
    const float* Ac  = (const float*)d_in[2];   // (NCH, 5)
    float* out = (float*)d_out;                 // (BS, NCH, NFRM)

    // workspace: zs (NH*NSEQ float4 = 8.26 MB) | G1 | G2 | y4f (1.03 MB each)
    float* zs  = (float*)d_ws;
    float* G1  = zs + (size_t)NH * NSEQ * 4;
    float* G2  = G1 + (size_t)NBK * NCH;
    float* y4f = G2 + (size_t)NBK * NCH;

    float alpha  = (float)exp(-1.0 / 128.0);
    float beta   = (float)exp(-1.0 / 8.0);
    float alphaL = (float)exp(-256.0 / 128.0);   // alpha^256 (frame step)
    float alphaH = (float)exp(-128.0 / 128.0);   // alpha^128

    // --- try cooperative mega with an occupancy-validated grid ---
    bool coop_ok = false;
    int occ = 0;
    hipError_t qe = hipOccupancyMaxActiveBlocksPerMultiprocessor(
        &occ, (const void*)mega, 256, 0);
    if (qe == hipSuccess && occ > 0) {
        int grid = occ * 256;                // 256 CUs
        if (grid > MAXGRID) grid = MAXGRID;
        void* args[] = {
            (void*)&wav, (void*)&Bc, (void*)&Ac, (void*)&zs,
            (void*)&G1, (void*)&G2, (void*)&y4f, (void*)&out,
            (void*)&alpha, (void*)&beta, (void*)&alphaL, (void*)&alphaH
        };
        hipError_t le = hipLaunchCooperativeKernel(
            (const void*)mega, dim3(grid), dim3(256), args, 0, stream);
        coop_ok = (le == hipSuccess);
    }
    if (!coop_ok) {
        (void)hipGetLastError();             // clear error state
        kA_forced_state<<<KA_EDGE + (NT + 1) / 2, 128, 0, stream>>>(wav, Bc, Ac, zs);
        kB_scan_par<<<(NSEQ + 3) / 4, 256, 0, stream>>>(Ac, zs);
        kC_main<<<KC_EDGE + KC_MAIN, 256, 0, stream>>>(wav, Bc, Ac, zs, G1, G2, y4f, beta, alpha);
        kD_scan_par<<<(NSEQ + 3) / 4, 256, 0, stream>>>(G1, G2, y4f, out, alpha, alphaL, alphaH);
    }
}

// Round 11
// 175.424 us; speedup vs baseline: 1.9575x; 1.9575x over previous
//
#include <hip/hip_runtime.h>
#include <math.h>

// Problem constants (from reference)
#define NCH 129
#define BS 8
#define TLEN 64000
#define HALF 128          // state granularity AND kC tile length
#define NH 500            // TLEN / HALF
#define LFRM 256          // frame stride
#define NFRM 250          // number of frames
#define NSEQ (NCH * BS)   // 1032 sequences
#define NBK (BS * NFRM)   // 2000 (b,frame) cells
#define NT (BS * NH)      // 4000 (b,tile) cells
#define KC_EDGE 16        // ceil(NT/256): phase-C channel-128 blocks
#define KC_MAIN (NT / 4)  // 1000 main blocks (4 tiles per 256-thr block)

typedef float f2 __attribute__((ext_vector_type(2)));

__device__ __forceinline__ f2 mk2(float a, float b) { f2 r; r.x = a; r.y = b; return r; }

__device__ __forceinline__ f2 fma2(f2 a, f2 b, f2 c) {
#if __has_builtin(__builtin_elementwise_fma)
    return __builtin_elementwise_fma(a, b, c);
#else
    f2 r; r.x = fmaf(a.x, b.x, c.x); r.y = fmaf(a.y, b.y, c.y); return r;
#endif
}

__device__ __forceinline__ f2 sig2(f2 v) {
    f2 r;
    r.x = __builtin_amdgcn_rcpf(1.0f + __expf(-v.x));
    r.y = __builtin_amdgcn_rcpf(1.0f + __expf(-v.y));
    return r;
}

// Packed pair-of-chains coefficients.
struct C2 { f2 b0, b1, b2, b3, b4, a1, a2, a3, a4; };

__device__ __forceinline__ C2 load_coef2(const float* __restrict__ B,
                                         const float* __restrict__ A,
                                         int cx, int cy) {
    C2 q;
    q.b0 = mk2(B[cx * 5 + 0], B[cy * 5 + 0]);
    q.b1 = mk2(B[cx * 5 + 1], B[cy * 5 + 1]);
    q.b2 = mk2(B[cx * 5 + 2], B[cy * 5 + 2]);
    q.b3 = mk2(B[cx * 5 + 3], B[cy * 5 + 3]);
    q.b4 = mk2(B[cx * 5 + 4], B[cy * 5 + 4]);
    q.a1 = mk2(A[cx * 5 + 1], A[cy * 5 + 1]);
    q.a2 = mk2(A[cx * 5 + 2], A[cy * 5 + 2]);
    q.a3 = mk2(A[cx * 5 + 3], A[cy * 5 + 3]);
    q.a4 = mk2(A[cx * 5 + 4], A[cy * 5 + 4]);
    return q;
}

__device__ __forceinline__ f2 iir2_step(const C2& q, float x,
                                        f2& z0, f2& z1, f2& z2, f2& z3) {
    f2 xx = mk2(x, x);
    f2 y = fma2(q.b0, xx, z0);
    z0 = fma2(-q.a1, y, fma2(q.b1, xx, z1));
    z1 = fma2(-q.a2, y, fma2(q.b2, xx, z2));
    z2 = fma2(-q.a3, y, fma2(q.b3, xx, z3));
    z3 = fma2(-q.a4, y, q.b4 * xx);
    return y;
}

// Scalar variants (kAB: wave-uniform coefficients -> SGPR operands).
struct Coef { float b0, b1, b2, b3, b4, a1, a2, a3, a4; };
__device__ __forceinline__ Coef load_coef(const float* __restrict__ B,
                                          const float* __restrict__ A, int c) {
    Coef q;
    q.b0 = B[c * 5 + 0]; q.b1 = B[c * 5 + 1]; q.b2 = B[c * 5 + 2];
    q.b3 = B[c * 5 + 3]; q.b4 = B[c * 5 + 4];
    q.a1 = A[c * 5 + 1]; q.a2 = A[c * 5 + 2];
    q.a3 = A[c * 5 + 3]; q.a4 = A[c * 5 + 4];
    return q;
}
__device__ __forceinline__ float iir_step(const Coef& q, float x,
                                          float& z0, float& z1, float& z2, float& z3) {
    float y = fmaf(q.b0, x, z0);
    z0 = fmaf(-q.a1, y, fmaf(q.b1, x, z1));
    z1 = fmaf(-q.a2, y, fmaf(q.b2, x, z2));
    z2 = fmaf(-q.a3, y, fmaf(q.b3, x, z3));
    z3 = fmaf(-q.a4, y, q.b4 * x);
    return y;
}

// step macros for packed chains
#define ISTEP(xv) { (void)iir2_step(q, (xv), z0, z1, z2, z3); }
#define WSTEP(xv)                                                              \
    { f2 y_ = iir2_step(q, (xv), z0, z1, z2, z3);                              \
      u = fma2(beta2, u, sig2(y_)); }
#define MSTEP(xv)                                                              \
    { f2 y_ = iir2_step(q, (xv), z0, z1, z2, z3);                              \
      u = fma2(beta2, u, sig2(y_));                                            \
      float un_ = __shfl_down(u.x, 1, 64);                                     \
      float y4o_ = fmaxf(u.y - u.x, 0.0f);                                     \
      float y4e_ = fmaxf(pend_un - pend_ub, 0.0f);                             \
      g2 = fma2(alpha2, g2, mk2(y4o_, y4e_));                                  \
      pend_un = un_; pend_ub = u.y; }

// ---- 4x4 matrix helpers over 16 NAMED scalars (no arrays -> no scratch) ----
#define MDECL(X) float X##00, X##01, X##02, X##03, X##10, X##11, X##12, X##13, \
                       X##20, X##21, X##22, X##23, X##30, X##31, X##32, X##33
#define MCOPY(D, S) D##00=S##00; D##01=S##01; D##02=S##02; D##03=S##03;        \
                    D##10=S##10; D##11=S##11; D##12=S##12; D##13=S##13;        \
                    D##20=S##20; D##21=S##21; D##22=S##22; D##23=S##23;        \
                    D##30=S##30; D##31=S##31; D##32=S##32; D##33=S##33
#define MROW(R, X, Y, i)                                                       \
    R##i##0 = fmaf(X##i##0, Y##00, fmaf(X##i##1, Y##10, fmaf(X##i##2, Y##20, X##i##3 * Y##30))); \
    R##i##1 = fmaf(X##i##0, Y##01, fmaf(X##i##1, Y##11, fmaf(X##i##2, Y##21, X##i##3 * Y##31))); \
    R##i##2 = fmaf(X##i##0, Y##02, fmaf(X##i##1, Y##12, fmaf(X##i##2, Y##22, X##i##3 * Y##32))); \
    R##i##3 = fmaf(X##i##0, Y##03, fmaf(X##i##1, Y##13, fmaf(X##i##2, Y##23, X##i##3 * Y##33)))
#define MMUL(R, X, Y) MROW(R, X, Y, 0); MROW(R, X, Y, 1); MROW(R, X, Y, 2); MROW(R, X, Y, 3)
#define MV(r, X, v)                                                            \
    r.x = fmaf(X##00, v.x, fmaf(X##01, v.y, fmaf(X##02, v.z, X##03 * v.w)));   \
    r.y = fmaf(X##10, v.x, fmaf(X##11, v.y, fmaf(X##12, v.z, X##13 * v.w)));   \
    r.z = fmaf(X##20, v.x, fmaf(X##21, v.y, fmaf(X##22, v.z, X##23 * v.w)));   \
    r.w = fmaf(X##30, v.x, fmaf(X##31, v.y, fmaf(X##32, v.z, X##33 * v.w)))

// kAB macros: per-lane chunk IIR (d kept in registers), fold, replay.
#define AB_CHUNK(dn, i)                                                        \
    {   int hh = h0 + (i);                                                     \
        float z0 = 0.f, z1 = 0.f, z2 = 0.f, z3 = 0.f;                          \
        if (hh < NH) {                                                         \
            const float4* xc = xb + (size_t)hh * (HALF / 4);                   \
            _Pragma("unroll 4")                                                \
            for (int g = 0; g < HALF / 4; ++g) {                               \
                float4 xq = xc[g];                                             \
                (void)iir_step(q, xq.x, z0, z1, z2, z3);                       \
                (void)iir_step(q, xq.y, z0, z1, z2, z3);                       \
                (void)iir_step(q, xq.z, z0, z1, z2, z3);                       \
                (void)iir_step(q, xq.w, z0, z1, z2, z3);                       \
            }                                                                  \
        }                                                                      \
        dn = make_float4(z0, z1, z2, z3); }
#define KB_FOLD(dn)                                                            \
    {   float4 t_; MV(t_, M1, e);                                              \
        e.x = t_.x + dn.x; e.y = t_.y + dn.y;                                  \
        e.z = t_.z + dn.z; e.w = t_.w + dn.w; }
#define KB_REPLAY(dn, i)                                                       \
    {   int hh = h0 + (i);                                                     \
        if (hh < NH) zbw[(size_t)hh * NSEQ + id] = zz;                         \
        float4 t_; MV(t_, M1, zz);                                             \
        zz.x = t_.x + dn.x; zz.y = t_.y + dn.y;                                \
        zz.z = t_.z + dn.z; zz.w = t_.w + dn.w; }

// phase-D macros
#define KD_LOAD(gn, yn, i)                                                     \
    {   int kk = k0 + (i); int kcl = (kk < NFRM) ? kk : (NFRM - 1);            \
        size_t ix = ((size_t)b * NFRM + kcl) * NCH + c;                        \
        gn = fmaf(aH, G1[ix], G2[ix]); yn = y4f[ix];                           \
        if (kk >= NFRM) { gn = 0.f; yn = 0.f; } }
#define KD_REPLAY(gn, yn, i)                                                   \
    {   int kk = k0 + (i);                                                     \
        if (kk < NFRM) o[kk] = fmaf(alpha, sv, yn);                            \
        sv = fmaf(aL, sv, gn); }

// ---------------------------------------------------------------------------
// Kernel AB (fused): one wave per (c,b) sequence. Lane l:
//   1) runs the 8 zero-init chunk IIRs for h in [8l, 8l+8) (d in registers;
//      coefficients wave-uniform -> SGPR operands),
//   2) fold:  e = Sum_i M128^{7-i} d_i,
//   3) Kogge-Stone over lanes with P = (M128^8)^{2^s},
//   4) exclusive shift, replay 8 steps storing exact states z_in[h] -> zs.
// Bit-identical to the round-8 kA+kB pair (same op order), minus one kernel
// boundary and the d-vector zs round-trip.
// ---------------------------------------------------------------------------
__global__ __launch_bounds__(256, 2) void kAB(
        const float* __restrict__ wav, const float* __restrict__ B,
        const float* __restrict__ A, float* __restrict__ zs) {
    int id = blockIdx.x * 4 + (threadIdx.x >> 6);   // sequence c*BS + b
    int lane = threadIdx.x & 63;
    if (id >= NSEQ) return;
    int c = id >> 3;                  // / BS
    int b = id & 7;                   // % BS
    Coef q = load_coef(B, A, c);      // wave-uniform
    const float4* xb = (const float4*)(wav + (size_t)b * TLEN);
    int h0 = lane * 8;

    // 1) chunk IIRs (d in named registers)
    float4 d0, d1, d2, d3, d4, d5, d6, d7;
    AB_CHUNK(d0, 0); AB_CHUNK(d1, 1); AB_CHUNK(d2, 2); AB_CHUNK(d3, 3);
    AB_CHUNK(d4, 4); AB_CHUNK(d5, 5); AB_CHUNK(d6, 6); AB_CHUNK(d7, 7);

    // transition matrices: M1 = M^128 (7 squarings), P = M1^8 (3 squarings)
    MDECL(M1);
    M100 = -q.a1; M101 = 1.f; M102 = 0.f; M103 = 0.f;
    M110 = -q.a2; M111 = 0.f; M112 = 1.f; M113 = 0.f;
    M120 = -q.a3; M121 = 0.f; M122 = 0.f; M123 = 1.f;
    M130 = -q.a4; M131 = 0.f; M132 = 0.f; M133 = 0.f;
    for (int s = 0; s < 7; ++s) {
        MDECL(T); MMUL(T, M1, M1); MCOPY(M1, T);
    }
    MDECL(P);
    MCOPY(P, M1);
    for (int s = 0; s < 3; ++s) {
        MDECL(T); MMUL(T, P, P); MCOPY(P, T);
    }

    // 2) fold
    float4 e = d0;
    KB_FOLD(d1); KB_FOLD(d2); KB_FOLD(d3); KB_FOLD(d4);
    KB_FOLD(d5); KB_FOLD(d6); KB_FOLD(d7);

    // 3) Kogge-Stone over lanes
    for (int s = 0; s < 6; ++s) {
        int off = 1 << s;
        float4 src;
        src.x = __shfl_up(e.x, off, 64);
        src.y = __shfl_up(e.y, off, 64);
        src.z = __shfl_up(e.z, off, 64);
        src.w = __shfl_up(e.w, off, 64);
        if (lane < off) { src.x = 0.f; src.y = 0.f; src.z = 0.f; src.w = 0.f; }
        float4 t_; MV(t_, P, src);
        e.x += t_.x; e.y += t_.y; e.z += t_.z; e.w += t_.w;
        if (s < 5) { MDECL(T); MMUL(T, P, P); MCOPY(P, T); }
    }

    // 4) exclusive shift + replay
    float4 zz;
    zz.x = __shfl_up(e.x, 1, 64);
    zz.y = __shfl_up(e.y, 1, 64);
    zz.z = __shfl_up(e.z, 1, 64);
    zz.w = __shfl_up(e.w, 1, 64);
    if (lane == 0) { zz.x = 0.f; zz.y = 0.f; zz.z = 0.f; zz.w = 0.f; }
    float4* zbw = (float4*)zs;
    KB_REPLAY(d0, 0); KB_REPLAY(d1, 1); KB_REPLAY(d2, 2); KB_REPLAY(d3, 3);
    KB_REPLAY(d4, 4); KB_REPLAY(d5, 5); KB_REPLAY(d6, 6); KB_REPLAY(d7, 7);
}

// ---------------------------------------------------------------------------
// Kernel C (round-8 proven; bodies also correctness-verified inside round-10
// mega): half-frame tiles; warm-up 64 IIR-only + 64 full from exact state.
// Blocks [0, KC_EDGE): channel-128 path, one (b,r) cell per thread.
// Blocks [KC_EDGE, +KC_MAIN): pair-channel main, wave w -> tile blk*4+w.
// ---------------------------------------------------------------------------
__global__ __launch_bounds__(256, 8) void kC_main(
        const float* __restrict__ wav, const float* __restrict__ B,
        const float* __restrict__ A, const float* __restrict__ zs,
        float* __restrict__ G1, float* __restrict__ G2,
        float* __restrict__ y4f, float beta, float alpha) {
    __shared__ float4 xs4[4 * 64];
    int blk = blockIdx.x;
    const f2 beta2 = mk2(beta, beta);
    const f2 alpha2 = mk2(alpha, alpha);

    if (blk < KC_EDGE) {
        int cell = blk * 256 + threadIdx.x;
        if (cell >= NT) return;
        int b = cell / NH;
        int r = cell - b * NH;
        int k = r >> 1, half = r & 1;
        C2 q = load_coef2(B, A, 127, 128);
        f2 z0 = mk2(0.f, 0.f), z1 = z0, z2 = z0, z3 = z0, u = z0;
        const float* xg;
        if (r > 0) {
            float4 vx = ((const float4*)zs)[(size_t)(r - 1) * NSEQ + (127 * BS + b)];
            float4 vy = ((const float4*)zs)[(size_t)(r - 1) * NSEQ + (128 * BS + b)];
            z0 = mk2(vx.x, vy.x); z1 = mk2(vx.y, vy.y);
            z2 = mk2(vx.z, vy.z); z3 = mk2(vx.w, vy.w);
            xg = wav + (size_t)b * TLEN + (size_t)(r - 1) * HALF;
            #pragma unroll 2
            for (int j = 0; j < HALF / 2; ++j) ISTEP(xg[j]);
            #pragma unroll 2
            for (int j = HALF / 2; j < HALF; ++j) WSTEP(xg[j]);
            xg += HALF;
        } else {
            xg = wav + (size_t)b * TLEN;
        }
        float g4 = 0.f, yfirst = 0.f;
        #pragma unroll 2
        for (int j = 0; j < HALF; ++j) {
            f2 y_ = iir2_step(q, xg[j], z0, z1, z2, z3);
            u = fma2(beta2, u, sig2(y_));
            float y4 = fmaxf(u.y - u.x, 0.0f);   // ch128 - ch127
            if (j == 0) yfirst = y4;
            g4 = fmaf(alpha, g4, y4);
        }
        size_t idx = ((size_t)b * NFRM + k) * NCH + 128;
        if (half == 0) { G1[idx] = g4; y4f[idx] = yfirst; }
        else           { G2[idx] = g4; }
        return;
    }

    // main: wave w handles tile (blk-KC_EDGE)*4 + w
    int wave = threadIdx.x >> 6;
    int lane = threadIdx.x & 63;
    int tile = (blk - KC_EDGE) * 4 + wave;   // < NT
    int b = tile / NH;
    int r = tile - b * NH;
    int k = r >> 1, half = r & 1;
    int n4 = (r > 0) ? 64 : 32;
    const float* xg = wav + (size_t)b * TLEN +
                      ((r > 0) ? (size_t)(r - 1) * HALF : (size_t)0);
    float4* seg = xs4 + wave * 64;
    if (lane < n4) seg[lane] = ((const float4*)xg)[lane];
    __syncthreads();

    int t = lane;
    int cA = 2 * t, cB2 = 2 * t + 1;
    C2 q = load_coef2(B, A, cA, cB2);
    f2 z0 = mk2(0.f, 0.f), z1 = z0, z2 = z0, z3 = z0, u = z0;
    int gbase = 0;
    if (r > 0) {
        float4 vx = ((const float4*)zs)[(size_t)(r - 1) * NSEQ + (cA * BS + b)];
        float4 vy = ((const float4*)zs)[(size_t)(r - 1) * NSEQ + (cB2 * BS + b)];
        z0 = mk2(vx.x, vy.x); z1 = mk2(vx.y, vy.y);
        z2 = mk2(vx.z, vy.z); z3 = mk2(vx.w, vy.w);
        for (int g = 0; g < HALF / 8; ++g) {        // 64 steps IIR-only
            float4 xq = seg[g];
            ISTEP(xq.x); ISTEP(xq.y); ISTEP(xq.z); ISTEP(xq.w);
        }
        for (int g = HALF / 8; g < HALF / 4; ++g) { // 64 full warm
            float4 xq = seg[g];
            WSTEP(xq.x); WSTEP(xq.y); WSTEP(xq.z); WSTEP(xq.w);
        }
        gbase = HALF / 4;
    }
    f2 g2;
    float fo, fe, pend_un, pend_ub;
    {   // first group: peel j=0 and j=1
        float4 xq = seg[gbase];
        f2 y_ = iir2_step(q, xq.x, z0, z1, z2, z3);
        u = fma2(beta2, u, sig2(y_));
        float un_ = __shfl_down(u.x, 1, 64);
        float y4o_ = fmaxf(u.y - u.x, 0.0f);
        fo = y4o_;
        g2 = mk2(y4o_, 0.0f);
        pend_un = un_; pend_ub = u.y;
        y_ = iir2_step(q, xq.y, z0, z1, z2, z3);
        u = fma2(beta2, u, sig2(y_));
        un_ = __shfl_down(u.x, 1, 64);
        y4o_ = fmaxf(u.y - u.x, 0.0f);
        float y4e_ = fmaxf(pend_un - pend_ub, 0.0f);
        fe = y4e_;
        g2 = fma2(alpha2, g2, mk2(y4o_, y4e_));
        pend_un = un_; pend_ub = u.y;
        MSTEP(xq.z); MSTEP(xq.w);
    }
    for (int g = gbase + 1; g < gbase + HALF / 4; ++g) {
        float4 xq = seg[g];
        MSTEP(xq.x); MSTEP(xq.y); MSTEP(xq.z); MSTEP(xq.w);
    }
    float y4e_last = fmaxf(pend_un - pend_ub, 0.0f);
    float go = g2.x;
    float ge = fmaf(alpha, g2.y, y4e_last);
    size_t base = ((size_t)b * NFRM + k) * NCH;
    if (half == 0) {
        G1[base + cB2] = go;
        y4f[base + cB2] = fo;
        if (t < 63) {
            G1[base + cB2 + 1] = ge;
            y4f[base + cB2 + 1] = fe;
        }
    } else {
        G2[base + cB2] = go;
        if (t < 63) G2[base + cB2 + 1] = ge;
    }
}

// ---------------------------------------------------------------------------
// Kernel D (round-8 proven): parallel alpha-scan, one wave per (b,c).
//   o[k] = alpha*s + y4f[k];  s' = aL*s + (aH*G1[k] + G2[k]).
// ---------------------------------------------------------------------------
__global__ __launch_bounds__(256) void kD_scan_par(
        const float* __restrict__ G1, const float* __restrict__ G2,
        const float* __restrict__ y4f, float* __restrict__ out,
        float alpha, float aL, float aH) {
    int id = blockIdx.x * 4 + (threadIdx.x >> 6);   // b * NCH + c
    int lane = threadIdx.x & 63;
    if (id >= NSEQ) return;
    int b = id / NCH;
    int c = id - b * NCH;
    float* o = out + (size_t)id * NFRM;
    int k0 = lane * 4;
    if (c == 0) {
        #pragma unroll
        for (int i = 0; i < 4; ++i) {
            int kk = k0 + i;
            if (kk < NFRM) o[kk] = 0.0f;
        }
        return;
    }
    float g0, g1, g2v, g3, y0, y1, y2v, y3;
    KD_LOAD(g0, y0, 0); KD_LOAD(g1, y1, 1); KD_LOAD(g2v, y2v, 2); KD_LOAD(g3, y3, 3);
    float e = g0;
    e = fmaf(aL, e, g1);
    e = fmaf(aL, e, g2v);
    e = fmaf(aL, e, g3);
    float aL2 = aL * aL;
    float f = aL2 * aL2;                 // aL^4
    for (int s = 0; s < 6; ++s) {
        int off = 1 << s;
        float src = __shfl_up(e, off, 64);
        if (lane < off) src = 0.f;
        e = fmaf(f, src, e);
        f = f * f;
    }
    float sv = __shfl_up(e, 1, 64);
    if (lane == 0) sv = 0.f;
    KD_REPLAY(g0, y0, 0); KD_REPLAY(g1, y1, 1);
    KD_REPLAY(g2v, y2v, 2); KD_REPLAY(g3, y3, 3);
}

// ---------------------------------------------------------------------------
extern "C" void kernel_launch(void* const* d_in, const int* in_sizes, int n_in,
                              void* d_out, int out_size, void* d_ws, size_t ws_size,
                              hipStream_t stream) {
    const float* wav = (const float*)d_in[0];   // (BS, TLEN)
    const float* Bc  = (const float*)d_in[1];   // (NCH, 5)
    const float* Ac  = (const float*)d_in[2];   // (NCH, 5)
    float* out = (float*)d_out;                 // (BS, NCH, NFRM)

    // workspace: zs (NH*NSEQ float4 = 8.26 MB) | G1 | G2 | y4f (1.03 MB each)
    float* zs  = (float*)d_ws;
    float* G1  = zs + (size_t)NH * NSEQ * 4;
    float* G2  = G1 + (size_t)NBK * NCH;
    float* y4f = G2 + (size_t)NBK * NCH;

    const float alpha  = (float)exp(-1.0 / 128.0);
    const float beta   = (float)exp(-1.0 / 8.0);
    const float alphaL = (float)exp(-256.0 / 128.0);   // alpha^256 (frame step)
    const float alphaH = (float)exp(-128.0 / 128.0);   // alpha^128

    kAB<<<(NSEQ + 3) / 4, 256, 0, stream>>>(wav, Bc, Ac, zs);
    kC_main<<<KC_EDGE + KC_MAIN, 256, 0, stream>>>(wav, Bc, Ac, zs, G1, G2, y4f, beta, alpha);
    kD_scan_par<<<(NSEQ + 3) / 4, 256, 0, stream>>>(G1, G2, y4f, out, alpha, alphaL, alphaH);
}

// Round 12
// 159.931 us; speedup vs baseline: 2.1471x; 1.0969x over previous
//
#include <hip/hip_runtime.h>
#include <math.h>

// Problem constants (from reference)
#define NCH 129
#define BS 8
#define TLEN 64000
#define HALF 128          // state granularity AND kC tile length
#define NH 500            // TLEN / HALF
#define LFRM 256          // frame stride
#define NFRM 250          // number of frames
#define NSEQ (NCH * BS)   // 1032 sequences
#define NBK (BS * NFRM)   // 2000 (b,frame) cells
#define NT (BS * NH)      // 4000 (b,tile) cells
#define NP (NT / 2)       // 2000 tile-pairs (tile r paired with r+250, same b)
#define KC_EDGE 16        // ceil(NT/256): channel-128 blocks
#define KC_MAIN (NP / 4)  // 500 main blocks (4 pairs per 256-thr block)
#define KA_EDGE 63        // ceil(NT/64): kA channel-128 blocks

typedef float f2 __attribute__((ext_vector_type(2)));

__device__ __forceinline__ f2 mk2(float a, float b) { f2 r; r.x = a; r.y = b; return r; }

__device__ __forceinline__ f2 fma2(f2 a, f2 b, f2 c) {
#if __has_builtin(__builtin_elementwise_fma)
    return __builtin_elementwise_fma(a, b, c);
#else
    f2 r; r.x = fmaf(a.x, b.x, c.x); r.y = fmaf(a.y, b.y, c.y); return r;
#endif
}

__device__ __forceinline__ f2 sig2(f2 v) {
    f2 r;
    r.x = __builtin_amdgcn_rcpf(1.0f + __expf(-v.x));
    r.y = __builtin_amdgcn_rcpf(1.0f + __expf(-v.y));
    return r;
}

// Packed pair-of-chains coefficients.
struct C2 { f2 b0, b1, b2, b3, b4, a1, a2, a3, a4; };

__device__ __forceinline__ C2 load_coef2(const float* __restrict__ B,
                                         const float* __restrict__ A,
                                         int cx, int cy) {
    C2 q;
    q.b0 = mk2(B[cx * 5 + 0], B[cy * 5 + 0]);
    q.b1 = mk2(B[cx * 5 + 1], B[cy * 5 + 1]);
    q.b2 = mk2(B[cx * 5 + 2], B[cy * 5 + 2]);
    q.b3 = mk2(B[cx * 5 + 3], B[cy * 5 + 3]);
    q.b4 = mk2(B[cx * 5 + 4], B[cy * 5 + 4]);
    q.a1 = mk2(A[cx * 5 + 1], A[cy * 5 + 1]);
    q.a2 = mk2(A[cx * 5 + 2], A[cy * 5 + 2]);
    q.a3 = mk2(A[cx * 5 + 3], A[cy * 5 + 3]);
    q.a4 = mk2(A[cx * 5 + 4], A[cy * 5 + 4]);
    return q;
}

__device__ __forceinline__ f2 iir2_step(const C2& q, float x,
                                        f2& z0, f2& z1, f2& z2, f2& z3) {
    f2 xx = mk2(x, x);
    f2 y = fma2(q.b0, xx, z0);
    z0 = fma2(-q.a1, y, fma2(q.b1, xx, z1));
    z1 = fma2(-q.a2, y, fma2(q.b2, xx, z2));
    z2 = fma2(-q.a3, y, fma2(q.b3, xx, z3));
    z3 = fma2(-q.a4, y, q.b4 * xx);
    return y;
}

// Scalar variants (kernel A).
struct Coef { float b0, b1, b2, b3, b4, a1, a2, a3, a4; };
__device__ __forceinline__ Coef load_coef(const float* __restrict__ B,
                                          const float* __restrict__ A, int c) {
    Coef q;
    q.b0 = B[c * 5 + 0]; q.b1 = B[c * 5 + 1]; q.b2 = B[c * 5 + 2];
    q.b3 = B[c * 5 + 3]; q.b4 = B[c * 5 + 4];
    q.a1 = A[c * 5 + 1]; q.a2 = A[c * 5 + 2];
    q.a3 = A[c * 5 + 3]; q.a4 = A[c * 5 + 4];
    return q;
}
__device__ __forceinline__ float iir_step(const Coef& q, float x,
                                          float& z0, float& z1, float& z2, float& z3) {
    float y = fmaf(q.b0, x, z0);
    z0 = fmaf(-q.a1, y, fmaf(q.b1, x, z1));
    z1 = fmaf(-q.a2, y, fmaf(q.b2, x, z2));
    z2 = fmaf(-q.a3, y, fmaf(q.b3, x, z3));
    z3 = fmaf(-q.a4, y, q.b4 * x);
    return y;
}

// ---- single-tile step macros (edge path) ----
#define ISTEP(xv) { (void)iir2_step(q, (xv), z0, z1, z2, z3); }
#define WSTEP(xv)                                                              \
    { f2 y_ = iir2_step(q, (xv), z0, z1, z2, z3);                              \
      u = fma2(beta2, u, sig2(y_)); }

// ---- dual-tile (ILP-2) step macros: tiles A and B share coefs q ----
#define ISTEP2(xa, xb2)                                                        \
    { (void)iir2_step(q, (xa), zA0, zA1, zA2, zA3);                            \
      (void)iir2_step(q, (xb2), zB0, zB1, zB2, zB3); }
#define ISTEPB(xb2) { (void)iir2_step(q, (xb2), zB0, zB1, zB2, zB3); }
#define WSTEP2(xa, xb2)                                                        \
    { f2 yA_ = iir2_step(q, (xa), zA0, zA1, zA2, zA3);                         \
      f2 yB_ = iir2_step(q, (xb2), zB0, zB1, zB2, zB3);                        \
      uA = fma2(beta2, uA, sig2(yA_));                                         \
      uB = fma2(beta2, uB, sig2(yB_)); }
#define WSTEPB(xb2)                                                            \
    { f2 yB_ = iir2_step(q, (xb2), zB0, zB1, zB2, zB3);                        \
      uB = fma2(beta2, uB, sig2(yB_)); }
#define MSTEP2(xa, xb2)                                                        \
    { f2 yA_ = iir2_step(q, (xa), zA0, zA1, zA2, zA3);                         \
      f2 yB_ = iir2_step(q, (xb2), zB0, zB1, zB2, zB3);                        \
      uA = fma2(beta2, uA, sig2(yA_));                                         \
      uB = fma2(beta2, uB, sig2(yB_));                                         \
      float unA_ = __shfl_down(uA.x, 1, 64);                                   \
      float unB_ = __shfl_down(uB.x, 1, 64);                                   \
      float y4oA_ = fmaxf(uA.y - uA.x, 0.0f);                                  \
      float y4eA_ = fmaxf(pAun - pAub, 0.0f);                                  \
      float y4oB_ = fmaxf(uB.y - uB.x, 0.0f);                                  \
      float y4eB_ = fmaxf(pBun - pBub, 0.0f);                                  \
      gA = fma2(alpha2, gA, mk2(y4oA_, y4eA_));                                \
      gB = fma2(alpha2, gB, mk2(y4oB_, y4eB_));                                \
      pAun = unA_; pAub = uA.y; pBun = unB_; pBub = uB.y; }

// ---- 4x4 matrix helpers over 16 NAMED scalars (no arrays -> no scratch) ----
#define MDECL(X) float X##00, X##01, X##02, X##03, X##10, X##11, X##12, X##13, \
                       X##20, X##21, X##22, X##23, X##30, X##31, X##32, X##33
#define MCOPY(D, S) D##00=S##00; D##01=S##01; D##02=S##02; D##03=S##03;        \
                    D##10=S##10; D##11=S##11; D##12=S##12; D##13=S##13;        \
                    D##20=S##20; D##21=S##21; D##22=S##22; D##23=S##23;        \
                    D##30=S##30; D##31=S##31; D##32=S##32; D##33=S##33
#define MROW(R, X, Y, i)                                                       \
    R##i##0 = fmaf(X##i##0, Y##00, fmaf(X##i##1, Y##10, fmaf(X##i##2, Y##20, X##i##3 * Y##30))); \
    R##i##1 = fmaf(X##i##0, Y##01, fmaf(X##i##1, Y##11, fmaf(X##i##2, Y##21, X##i##3 * Y##31))); \
    R##i##2 = fmaf(X##i##0, Y##02, fmaf(X##i##1, Y##12, fmaf(X##i##2, Y##22, X##i##3 * Y##32))); \
    R##i##3 = fmaf(X##i##0, Y##03, fmaf(X##i##1, Y##13, fmaf(X##i##2, Y##23, X##i##3 * Y##33)))
#define MMUL(R, X, Y) MROW(R, X, Y, 0); MROW(R, X, Y, 1); MROW(R, X, Y, 2); MROW(R, X, Y, 3)
#define MV(r, X, v)                                                            \
    r.x = fmaf(X##00, v.x, fmaf(X##01, v.y, fmaf(X##02, v.z, X##03 * v.w)));   \
    r.y = fmaf(X##10, v.x, fmaf(X##11, v.y, fmaf(X##12, v.z, X##13 * v.w)));   \
    r.z = fmaf(X##20, v.x, fmaf(X##21, v.y, fmaf(X##22, v.z, X##23 * v.w)));   \
    r.w = fmaf(X##30, v.x, fmaf(X##31, v.y, fmaf(X##32, v.z, X##33 * v.w)))

// phase-B macros
#define KB_LOAD(dn, i)                                                         \
    {   int hh = h0 + (i); int hcl = (hh < NH) ? hh : (NH - 1);                \
        dn = zb[(size_t)hcl * NSEQ + id];                                      \
        if (hh >= NH) dn = make_float4(0.f, 0.f, 0.f, 0.f); }
#define KB_FOLD(dn)                                                            \
    {   float4 t_; MV(t_, M1, e);                                              \
        e.x = t_.x + dn.x; e.y = t_.y + dn.y;                                  \
        e.z = t_.z + dn.z; e.w = t_.w + dn.w; }
#define KB_REPLAY(dn, i)                                                       \
    {   int hh = h0 + (i);                                                     \
        if (hh < NH) zbw[(size_t)hh * NSEQ + id] = zz;                         \
        float4 t_; MV(t_, M1, zz);                                             \
        zz.x = t_.x + dn.x; zz.y = t_.y + dn.y;                                \
        zz.z = t_.z + dn.z; zz.w = t_.w + dn.w; }

// phase-D macros
#define KD_LOAD(gn, yn, i)                                                     \
    {   int kk = k0 + (i); int kcl = (kk < NFRM) ? kk : (NFRM - 1);            \
        size_t ix = ((size_t)b * NFRM + kcl) * NCH + c;                        \
        gn = fmaf(aH, G1[ix], G2[ix]); yn = y4f[ix];                           \
        if (kk >= NFRM) { gn = 0.f; yn = 0.f; } }
#define KD_REPLAY(gn, yn, i)                                                   \
    {   int kk = k0 + (i);                                                     \
        if (kk < NFRM) o[kk] = fmaf(alpha, sv, yn);                            \
        sv = fmaf(aL, sv, gn); }

// ---------------------------------------------------------------------------
// Kernel A (round-8 proven): forced-response state per (c, b, half-chunk h).
// Blocks [0, KA_EDGE): channel 128 — one (b,h) item per lane (wave 0 only).
// Blocks [KA_EDGE, +NT): channels 0..127 — 128 threads, LDS-staged x.
// zs layout: float4 at [h * NSEQ + (c*BS+b)].
// ---------------------------------------------------------------------------
__global__ __launch_bounds__(128, 4) void kA_forced_state(
        const float* __restrict__ wav, const float* __restrict__ B,
        const float* __restrict__ A, float* __restrict__ zs) {
    __shared__ float xs[HALF];
    int blk = blockIdx.x;
    if (blk < KA_EDGE) {
        int item = blk * 64 + threadIdx.x;
        if (threadIdx.x >= 64 || item >= NT) return;
        int b = item / NH;
        int h = item - b * NH;
        const float* xg = wav + (size_t)b * TLEN + (size_t)h * HALF;
        Coef q = load_coef(B, A, 128);
        float z0 = 0.f, z1 = 0.f, z2 = 0.f, z3 = 0.f;
        #pragma unroll 4
        for (int j = 0; j < HALF; ++j) {
            (void)iir_step(q, xg[j], z0, z1, z2, z3);
        }
        ((float4*)zs)[(size_t)h * NSEQ + (128 * BS + b)] = make_float4(z0, z1, z2, z3);
        return;
    }
    int mblk = blk - KA_EDGE;        // b * NH + h
    int b = mblk / NH;
    int h = mblk - b * NH;
    const float* xg = wav + (size_t)b * TLEN + (size_t)h * HALF;
    xs[threadIdx.x] = xg[threadIdx.x];
    __syncthreads();
    int c = threadIdx.x;             // 0..127
    Coef q = load_coef(B, A, c);
    float z0 = 0.f, z1 = 0.f, z2 = 0.f, z3 = 0.f;
    #pragma unroll 8
    for (int j = 0; j < HALF; ++j) {
        (void)iir_step(q, xs[j], z0, z1, z2, z3);
    }
    ((float4*)zs)[(size_t)h * NSEQ + (c * BS + b)] = make_float4(z0, z1, z2, z3);
}

// ---------------------------------------------------------------------------
// Kernel B (round-8 proven): Kogge-Stone matrix scan, one wave per (c,b).
// ---------------------------------------------------------------------------
__global__ __launch_bounds__(256) void kB_scan_par(
        const float* __restrict__ A, float* __restrict__ zs) {
    int id = blockIdx.x * 4 + (threadIdx.x >> 6);   // c * BS + b
    int lane = threadIdx.x & 63;
    if (id >= NSEQ) return;
    int c = id / BS;
    float a1 = A[c * 5 + 1], a2 = A[c * 5 + 2], a3 = A[c * 5 + 3], a4 = A[c * 5 + 4];
    MDECL(M1);
    M100 = -a1; M101 = 1.f; M102 = 0.f; M103 = 0.f;
    M110 = -a2; M111 = 0.f; M112 = 1.f; M113 = 0.f;
    M120 = -a3; M121 = 0.f; M122 = 0.f; M123 = 1.f;
    M130 = -a4; M131 = 0.f; M132 = 0.f; M133 = 0.f;
    for (int s = 0; s < 7; ++s) {        // M^128
        MDECL(T); MMUL(T, M1, M1); MCOPY(M1, T);
    }
    MDECL(P);
    MCOPY(P, M1);
    for (int s = 0; s < 3; ++s) {        // P = M128^8
        MDECL(T); MMUL(T, P, P); MCOPY(P, T);
    }
    const float4* zb = (const float4*)zs;
    float4* zbw = (float4*)zs;
    int h0 = lane * 8;
    float4 d0, d1, d2, d3, d4, d5, d6, d7;
    KB_LOAD(d0, 0); KB_LOAD(d1, 1); KB_LOAD(d2, 2); KB_LOAD(d3, 3);
    KB_LOAD(d4, 4); KB_LOAD(d5, 5); KB_LOAD(d6, 6); KB_LOAD(d7, 7);
    float4 e = d0;
    KB_FOLD(d1); KB_FOLD(d2); KB_FOLD(d3); KB_FOLD(d4);
    KB_FOLD(d5); KB_FOLD(d6); KB_FOLD(d7);
    for (int s = 0; s < 6; ++s) {
        int off = 1 << s;
        float4 src;
        src.x = __shfl_up(e.x, off, 64);
        src.y = __shfl_up(e.y, off, 64);
        src.z = __shfl_up(e.z, off, 64);
        src.w = __shfl_up(e.w, off, 64);
        if (lane < off) { src.x = 0.f; src.y = 0.f; src.z = 0.f; src.w = 0.f; }
        float4 t_; MV(t_, P, src);
        e.x += t_.x; e.y += t_.y; e.z += t_.z; e.w += t_.w;
        if (s < 5) { MDECL(T); MMUL(T, P, P); MCOPY(P, T); }
    }
    float4 zz;
    zz.x = __shfl_up(e.x, 1, 64);
    zz.y = __shfl_up(e.y, 1, 64);
    zz.z = __shfl_up(e.z, 1, 64);
    zz.w = __shfl_up(e.w, 1, 64);
    if (lane == 0) { zz.x = 0.f; zz.y = 0.f; zz.z = 0.f; zz.w = 0.f; }
    KB_REPLAY(d0, 0); KB_REPLAY(d1, 1); KB_REPLAY(d2, 2); KB_REPLAY(d3, 3);
    KB_REPLAY(d4, 4); KB_REPLAY(d5, 5); KB_REPLAY(d6, 6); KB_REPLAY(d7, 7);
}

// ---------------------------------------------------------------------------
// Kernel C: ILP-2 pair-channel main pass.
// Blocks [0, KC_EDGE): channel-128 path — one (b,r) cell per thread (proven).
// Blocks [KC_EDGE, +KC_MAIN): wave w handles PAIR p = (blk-KC_EDGE)*4 + w:
//   tile A = (b, r1), tile B = (b, r1+250), r1 = p % 250, b = p / 250.
//   Same channel pair per lane for both tiles -> shared coef registers; the
//   two tiles' dependent chains are independent -> ILP hides trans/shfl
//   latency. Warm-up per tile: 64 IIR-only + 64 full (beta^64 truncation).
// ---------------------------------------------------------------------------
__global__ __launch_bounds__(256, 4) void kC_main(
        const float* __restrict__ wav, const float* __restrict__ B,
        const float* __restrict__ A, const float* __restrict__ zs,
        float* __restrict__ G1, float* __restrict__ G2,
        float* __restrict__ y4f, float beta, float alpha) {
    __shared__ float4 xs4[4][2][64];   // [wave][tile][group]
    int blk = blockIdx.x;
    const f2 beta2 = mk2(beta, beta);
    const f2 alpha2 = mk2(alpha, alpha);

    if (blk < KC_EDGE) {
        // ---- edge: channel 128, one (b,r) per thread ----
        int cell = blk * 256 + threadIdx.x;
        if (cell >= NT) return;
        int b = cell / NH;
        int r = cell - b * NH;
        int k = r >> 1, half = r & 1;
        C2 q = load_coef2(B, A, 127, 128);
        f2 z0 = mk2(0.f, 0.f), z1 = z0, z2 = z0, z3 = z0, u = z0;
        const float* xg;
        if (r > 0) {
            float4 vx = ((const float4*)zs)[(size_t)(r - 1) * NSEQ + (127 * BS + b)];
            float4 vy = ((const float4*)zs)[(size_t)(r - 1) * NSEQ + (128 * BS + b)];
            z0 = mk2(vx.x, vy.x); z1 = mk2(vx.y, vy.y);
            z2 = mk2(vx.z, vy.z); z3 = mk2(vx.w, vy.w);
            xg = wav + (size_t)b * TLEN + (size_t)(r - 1) * HALF;
            #pragma unroll 2
            for (int j = 0; j < HALF / 2; ++j) ISTEP(xg[j]);
            #pragma unroll 2
            for (int j = HALF / 2; j < HALF; ++j) WSTEP(xg[j]);
            xg += HALF;
        } else {
            xg = wav + (size_t)b * TLEN;
        }
        float g4 = 0.f, yfirst = 0.f;
        #pragma unroll 2
        for (int j = 0; j < HALF; ++j) {
            f2 y_ = iir2_step(q, xg[j], z0, z1, z2, z3);
            u = fma2(beta2, u, sig2(y_));
            float y4 = fmaxf(u.y - u.x, 0.0f);   // ch128 - ch127
            if (j == 0) yfirst = y4;
            g4 = fmaf(alpha, g4, y4);
        }
        size_t idx = ((size_t)b * NFRM + k) * NCH + 128;
        if (half == 0) { G1[idx] = g4; y4f[idx] = yfirst; }
        else           { G2[idx] = g4; }
        return;
    }

    // ---- main: wave w -> pair p; tiles (b,r1) and (b,r1+250) ----
    int wave = threadIdx.x >> 6;
    int lane = threadIdx.x & 63;
    int p = (blk - KC_EDGE) * 4 + wave;      // < NP = 2000
    int b = p / NFRM;
    int r1 = p - b * NFRM;                   // 0..249
    int r2 = r1 + NFRM;                      // 250..499 (always > 0)

    const float* xgA = wav + (size_t)b * TLEN +
                       ((r1 > 0) ? (size_t)(r1 - 1) * HALF : (size_t)0);
    const float* xgB = wav + (size_t)b * TLEN + (size_t)(r2 - 1) * HALF;
    int n4A = (r1 > 0) ? 64 : 32;
    float4* segA = &xs4[wave][0][0];
    float4* segB = &xs4[wave][1][0];
    if (lane < n4A) segA[lane] = ((const float4*)xgA)[lane];
    segB[lane] = ((const float4*)xgB)[lane];
    __syncthreads();

    int cA = 2 * lane, cB2 = 2 * lane + 1;
    C2 q = load_coef2(B, A, cA, cB2);        // shared by both tiles
    f2 zA0 = mk2(0.f, 0.f), zA1 = zA0, zA2 = zA0, zA3 = zA0, uA = zA0;
    f2 zB0 = zA0, zB1 = zA0, zB2 = zA0, zB3 = zA0, uB = zA0;

    // tile B warm state (always valid)
    {
        float4 vx = ((const float4*)zs)[(size_t)(r2 - 1) * NSEQ + (cA * BS + b)];
        float4 vy = ((const float4*)zs)[(size_t)(r2 - 1) * NSEQ + (cB2 * BS + b)];
        zB0 = mk2(vx.x, vy.x); zB1 = mk2(vx.y, vy.y);
        zB2 = mk2(vx.z, vy.z); zB3 = mk2(vx.w, vy.w);
    }
    int gbaseA = 0;
    if (r1 > 0) {                            // wave-uniform branch
        float4 vx = ((const float4*)zs)[(size_t)(r1 - 1) * NSEQ + (cA * BS + b)];
        float4 vy = ((const float4*)zs)[(size_t)(r1 - 1) * NSEQ + (cB2 * BS + b)];
        zA0 = mk2(vx.x, vy.x); zA1 = mk2(vx.y, vy.y);
        zA2 = mk2(vx.z, vy.z); zA3 = mk2(vx.w, vy.w);
        for (int g = 0; g < 16; ++g) {       // 64 steps IIR-only, both tiles
            float4 xqA = segA[g];
            float4 xqB = segB[g];
            ISTEP2(xqA.x, xqB.x); ISTEP2(xqA.y, xqB.y);
            ISTEP2(xqA.z, xqB.z); ISTEP2(xqA.w, xqB.w);
        }
        for (int g = 16; g < 32; ++g) {      // 64 full warm, both tiles
            float4 xqA = segA[g];
            float4 xqB = segB[g];
            WSTEP2(xqA.x, xqB.x); WSTEP2(xqA.y, xqB.y);
            WSTEP2(xqA.z, xqB.z); WSTEP2(xqA.w, xqB.w);
        }
        gbaseA = 32;
    } else {                                 // r1 == 0: warm tile B only
        for (int g = 0; g < 16; ++g) {
            float4 xqB = segB[g];
            ISTEPB(xqB.x); ISTEPB(xqB.y); ISTEPB(xqB.z); ISTEPB(xqB.w);
        }
        for (int g = 16; g < 32; ++g) {
            float4 xqB = segB[g];
            WSTEPB(xqB.x); WSTEPB(xqB.y); WSTEPB(xqB.z); WSTEPB(xqB.w);
        }
        gbaseA = 0;
    }

    // main 128 steps for both tiles; shfl consumed one step late per tile.
    f2 gA, gB;
    float foA, feA, foB, feB, pAun, pAub, pBun, pBub;
    {   // first group: peel j=0 and j=1
        float4 xqA = segA[gbaseA];
        float4 xqB = segB[32];
        // j = 0
        f2 yA_ = iir2_step(q, xqA.x, zA0, zA1, zA2, zA3);
        f2 yB_ = iir2_step(q, xqB.x, zB0, zB1, zB2, zB3);
        uA = fma2(beta2, uA, sig2(yA_));
        uB = fma2(beta2, uB, sig2(yB_));
        float unA_ = __shfl_down(uA.x, 1, 64);
        float unB_ = __shfl_down(uB.x, 1, 64);
        foA = fmaxf(uA.y - uA.x, 0.0f);
        foB = fmaxf(uB.y - uB.x, 0.0f);
        gA = mk2(foA, 0.0f);
        gB = mk2(foB, 0.0f);
        pAun = unA_; pAub = uA.y; pBun = unB_; pBub = uB.y;
        // j = 1
        yA_ = iir2_step(q, xqA.y, zA0, zA1, zA2, zA3);
        yB_ = iir2_step(q, xqB.y, zB0, zB1, zB2, zB3);
        uA = fma2(beta2, uA, sig2(yA_));
        uB = fma2(beta2, uB, sig2(yB_));
        unA_ = __shfl_down(uA.x, 1, 64);
        unB_ = __shfl_down(uB.x, 1, 64);
        float y4oA_ = fmaxf(uA.y - uA.x, 0.0f);
        float y4oB_ = fmaxf(uB.y - uB.x, 0.0f);
        feA = fmaxf(pAun - pAub, 0.0f);      // y4e at j=0
        feB = fmaxf(pBun - pBub, 0.0f);
        gA = fma2(alpha2, gA, mk2(y4oA_, feA));
        gB = fma2(alpha2, gB, mk2(y4oB_, feB));
        pAun = unA_; pAub = uA.y; pBun = unB_; pBub = uB.y;
        // j = 2, 3
        MSTEP2(xqA.z, xqB.z); MSTEP2(xqA.w, xqB.w);
    }
    for (int g = 1; g < 32; ++g) {
        float4 xqA = segA[gbaseA + g];
        float4 xqB = segB[32 + g];
        MSTEP2(xqA.x, xqB.x); MSTEP2(xqA.y, xqB.y);
        MSTEP2(xqA.z, xqB.z); MSTEP2(xqA.w, xqB.w);
    }
    // tails: apply last pending ge term per tile
    float goA = gA.x;
    float geA = fmaf(alpha, gA.y, fmaxf(pAun - pAub, 0.0f));
    float goB = gB.x;
    float geB = fmaf(alpha, gB.y, fmaxf(pBun - pBub, 0.0f));

    // stores: tile A -> frame r1>>1 (half r1&1); tile B -> frame r2>>1
    {
        int k = r1 >> 1, half = r1 & 1;
        size_t base = ((size_t)b * NFRM + k) * NCH;
        if (half == 0) {
            G1[base + cB2] = goA;
            y4f[base + cB2] = foA;
            if (lane < 63) {
                G1[base + cB2 + 1] = geA;
                y4f[base + cB2 + 1] = feA;
            }
        } else {
            G2[base + cB2] = goA;
            if (lane < 63) G2[base + cB2 + 1] = geA;
        }
    }
    {
        int k = r2 >> 1, half = r2 & 1;
        size_t base = ((size_t)b * NFRM + k) * NCH;
        if (half == 0) {
            G1[base + cB2] = goB;
            y4f[base + cB2] = foB;
            if (lane < 63) {
                G1[base + cB2 + 1] = geB;
                y4f[base + cB2 + 1] = feB;
            }
        } else {
            G2[base + cB2] = goB;
            if (lane < 63) G2[base + cB2 + 1] = geB;
        }
    }
}

// ---------------------------------------------------------------------------
// Kernel D (round-8 proven): parallel alpha-scan, one wave per (b,c).
//   o[k] = alpha*s + y4f[k];  s' = aL*s + (aH*G1[k] + G2[k]).
// ---------------------------------------------------------------------------
__global__ __launch_bounds__(256) void kD_scan_par(
        const float* __restrict__ G1, const float* __restrict__ G2,
        const float* __restrict__ y4f, float* __restrict__ out,
        float alpha, float aL, float aH) {
    int id = blockIdx.x * 4 + (threadIdx.x >> 6);   // b * NCH + c
    int lane = threadIdx.x & 63;
    if (id >= NSEQ) return;
    int b = id / NCH;
    int c = id - b * NCH;
    float* o = out + (size_t)id * NFRM;
    int k0 = lane * 4;
    if (c == 0) {
        #pragma unroll
        for (int i = 0; i < 4; ++i) {
            int kk = k0 + i;
            if (kk < NFRM) o[kk] = 0.0f;
        }
        return;
    }
    float g0, g1, g2v, g3, y0, y1, y2v, y3;
    KD_LOAD(g0, y0, 0); KD_LOAD(g1, y1, 1); KD_LOAD(g2v, y2v, 2); KD_LOAD(g3, y3, 3);
    float e = g0;
    e = fmaf(aL, e, g1);
    e = fmaf(aL, e, g2v);
    e = fmaf(aL, e, g3);
    float aL2 = aL * aL;
    float f = aL2 * aL2;                 // aL^4
    for (int s = 0; s < 6; ++s) {
        int off = 1 << s;
        float src = __shfl_up(e, off, 64);
        if (lane < off) src = 0.f;
        e = fmaf(f, src, e);
        f = f * f;
    }
    float sv = __shfl_up(e, 1, 64);
    if (lane == 0) sv = 0.f;
    KD_REPLAY(g0, y0, 0); KD_REPLAY(g1, y1, 1);
    KD_REPLAY(g2v, y2v, 2); KD_REPLAY(g3, y3, 3);
}

// ---------------------------------------------------------------------------
extern "C" void kernel_launch(void* const* d_in, const int* in_sizes, int n_in,
                              void* d_out, int out_size, void* d_ws, size_t ws_size,
                              hipStream_t stream) {
    const float* wav = (const float*)d_in[0];   // (BS, TLEN)
    const float* Bc  = (const float*)d_in[1];   // (NCH, 5)
    const float* Ac  = (const float*)d_in[2];   // (NCH, 5)
    float* out = (float*)d_out;                 // (BS, NCH, NFRM)

    // workspace: zs (NH*NSEQ float4 = 8.26 MB) | G1 | G2 | y4f (1.03 MB each)
    float* zs  = (float*)d_ws;
    float* G1  = zs + (size_t)NH * NSEQ * 4;
    float* G2  = G1 + (size_t)NBK * NCH;
    float* y4f = G2 + (size_t)NBK * NCH;

    const float alpha  = (float)exp(-1.0 / 128.0);
    const float beta   = (float)exp(-1.0 / 8.0);
    const float alphaL = (float)exp(-256.0 / 128.0);   // alpha^256 (frame step)
    const float alphaH = (float)exp(-128.0 / 128.0);   // alpha^128

    kA_forced_state<<<KA_EDGE + NT, 128, 0, stream>>>(wav, Bc, Ac, zs);
    kB_scan_par<<<(NSEQ + 3) / 4, 256, 0, stream>>>(Ac, zs);
    kC_main<<<KC_EDGE + KC_MAIN, 256, 0, stream>>>(wav, Bc, Ac, zs, G1, G2, y4f, beta, alpha);
    kD_scan_par<<<(NSEQ + 3) / 4, 256, 0, stream>>>(G1, G2, y4f, out, alpha, alphaL, alphaH);
}

// Round 13
// 154.355 us; speedup vs baseline: 2.2247x; 1.0361x over previous
//
#include <hip/hip_runtime.h>
#include <math.h>

// Problem constants (from reference)
#define NCH 129
#define BS 8
#define TLEN 64000
#define CH 64             // state granularity (zs every 64 samples)
#define NHF 1000          // TLEN / CH states per sequence
#define HALF 128          // kC tile length (main part)
#define NH 500            // TLEN / HALF tiles per sequence
#define NFRM 250          // number of frames
#define NSEQ (NCH * BS)   // 1032 sequences
#define NBK (BS * NFRM)   // 2000 (b,frame) cells
#define NT (BS * NH)      // 4000 (b,tile) cells
#define KA_EDGE 63        // ceil(NT/64): kA channel-128 blocks (2 chunks/cell)
#define KC_EDGE 16        // ceil(NT/256): kC channel-128 blocks
#define KC_MAIN (NT / 4)  // 1000 main blocks (4 tiles per 256-thr block)

typedef float f2 __attribute__((ext_vector_type(2)));

__device__ __forceinline__ f2 mk2(float a, float b) { f2 r; r.x = a; r.y = b; return r; }

__device__ __forceinline__ f2 fma2(f2 a, f2 b, f2 c) {
#if __has_builtin(__builtin_elementwise_fma)
    return __builtin_elementwise_fma(a, b, c);
#else
    f2 r; r.x = fmaf(a.x, b.x, c.x); r.y = fmaf(a.y, b.y, c.y); return r;
#endif
}

__device__ __forceinline__ f2 sig2(f2 v) {
    f2 r;
    r.x = __builtin_amdgcn_rcpf(1.0f + __expf(-v.x));
    r.y = __builtin_amdgcn_rcpf(1.0f + __expf(-v.y));
    return r;
}

// Packed pair-of-chains coefficients.
struct C2 { f2 b0, b1, b2, b3, b4, a1, a2, a3, a4; };

__device__ __forceinline__ C2 load_coef2(const float* __restrict__ B,
                                         const float* __restrict__ A,
                                         int cx, int cy) {
    C2 q;
    q.b0 = mk2(B[cx * 5 + 0], B[cy * 5 + 0]);
    q.b1 = mk2(B[cx * 5 + 1], B[cy * 5 + 1]);
    q.b2 = mk2(B[cx * 5 + 2], B[cy * 5 + 2]);
    q.b3 = mk2(B[cx * 5 + 3], B[cy * 5 + 3]);
    q.b4 = mk2(B[cx * 5 + 4], B[cy * 5 + 4]);
    q.a1 = mk2(A[cx * 5 + 1], A[cy * 5 + 1]);
    q.a2 = mk2(A[cx * 5 + 2], A[cy * 5 + 2]);
    q.a3 = mk2(A[cx * 5 + 3], A[cy * 5 + 3]);
    q.a4 = mk2(A[cx * 5 + 4], A[cy * 5 + 4]);
    return q;
}

__device__ __forceinline__ f2 iir2_step(const C2& q, float x,
                                        f2& z0, f2& z1, f2& z2, f2& z3) {
    f2 xx = mk2(x, x);
    f2 y = fma2(q.b0, xx, z0);
    z0 = fma2(-q.a1, y, fma2(q.b1, xx, z1));
    z1 = fma2(-q.a2, y, fma2(q.b2, xx, z2));
    z2 = fma2(-q.a3, y, fma2(q.b3, xx, z3));
    z3 = fma2(-q.a4, y, q.b4 * xx);
    return y;
}

// Scalar variants (kernel A).
struct Coef { float b0, b1, b2, b3, b4, a1, a2, a3, a4; };
__device__ __forceinline__ Coef load_coef(const float* __restrict__ B,
                                          const float* __restrict__ A, int c) {
    Coef q;
    q.b0 = B[c * 5 + 0]; q.b1 = B[c * 5 + 1]; q.b2 = B[c * 5 + 2];
    q.b3 = B[c * 5 + 3]; q.b4 = B[c * 5 + 4];
    q.a1 = A[c * 5 + 1]; q.a2 = A[c * 5 + 2];
    q.a3 = A[c * 5 + 3]; q.a4 = A[c * 5 + 4];
    return q;
}
__device__ __forceinline__ float iir_step(const Coef& q, float x,
                                          float& z0, float& z1, float& z2, float& z3) {
    float y = fmaf(q.b0, x, z0);
    z0 = fmaf(-q.a1, y, fmaf(q.b1, x, z1));
    z1 = fmaf(-q.a2, y, fmaf(q.b2, x, z2));
    z2 = fmaf(-q.a3, y, fmaf(q.b3, x, z3));
    z3 = fmaf(-q.a4, y, q.b4 * x);
    return y;
}

// step macros for packed chains
#define ISTEP(xv) { (void)iir2_step(q, (xv), z0, z1, z2, z3); }
#define WSTEP(xv)                                                              \
    { f2 y_ = iir2_step(q, (xv), z0, z1, z2, z3);                              \
      u = fma2(beta2, u, sig2(y_)); }
#define MSTEP(xv)                                                              \
    { f2 y_ = iir2_step(q, (xv), z0, z1, z2, z3);                              \
      u = fma2(beta2, u, sig2(y_));                                            \
      float un_ = __shfl_down(u.x, 1, 64);                                     \
      float y4o_ = fmaxf(u.y - u.x, 0.0f);                                     \
      float y4e_ = fmaxf(pend_un - pend_ub, 0.0f);                             \
      g2 = fma2(alpha2, g2, mk2(y4o_, y4e_));                                  \
      pend_un = un_; pend_ub = u.y; }

// ---- 4x4 matrix helpers over 16 NAMED scalars (no arrays -> no scratch) ----
#define MDECL(X) float X##00, X##01, X##02, X##03, X##10, X##11, X##12, X##13, \
                       X##20, X##21, X##22, X##23, X##30, X##31, X##32, X##33
#define MCOPY(D, S) D##00=S##00; D##01=S##01; D##02=S##02; D##03=S##03;        \
                    D##10=S##10; D##11=S##11; D##12=S##12; D##13=S##13;        \
                    D##20=S##20; D##21=S##21; D##22=S##22; D##23=S##23;        \
                    D##30=S##30; D##31=S##31; D##32=S##32; D##33=S##33
#define MROW(R, X, Y, i)                                                       \
    R##i##0 = fmaf(X##i##0, Y##00, fmaf(X##i##1, Y##10, fmaf(X##i##2, Y##20, X##i##3 * Y##30))); \
    R##i##1 = fmaf(X##i##0, Y##01, fmaf(X##i##1, Y##11, fmaf(X##i##2, Y##21, X##i##3 * Y##31))); \
    R##i##2 = fmaf(X##i##0, Y##02, fmaf(X##i##1, Y##12, fmaf(X##i##2, Y##22, X##i##3 * Y##32))); \
    R##i##3 = fmaf(X##i##0, Y##03, fmaf(X##i##1, Y##13, fmaf(X##i##2, Y##23, X##i##3 * Y##33)))
#define MMUL(R, X, Y) MROW(R, X, Y, 0); MROW(R, X, Y, 1); MROW(R, X, Y, 2); MROW(R, X, Y, 3)
#define MV(r, X, v)                                                            \
    r.x = fmaf(X##00, v.x, fmaf(X##01, v.y, fmaf(X##02, v.z, X##03 * v.w)));   \
    r.y = fmaf(X##10, v.x, fmaf(X##11, v.y, fmaf(X##12, v.z, X##13 * v.w)));   \
    r.z = fmaf(X##20, v.x, fmaf(X##21, v.y, fmaf(X##22, v.z, X##23 * v.w)));   \
    r.w = fmaf(X##30, v.x, fmaf(X##31, v.y, fmaf(X##32, v.z, X##33 * v.w)))

// phase-B macros (16 chunks per lane)
#define KB_LOAD(dn, i)                                                         \
    {   int hh = h0 + (i); int hcl = (hh < NHF) ? hh : (NHF - 1);              \
        dn = zb[(size_t)hcl * NSEQ + id];                                      \
        if (hh >= NHF) dn = make_float4(0.f, 0.f, 0.f, 0.f); }
#define KB_FOLD(dn)                                                            \
    {   float4 t_; MV(t_, M1, e);                                              \
        e.x = t_.x + dn.x; e.y = t_.y + dn.y;                                  \
        e.z = t_.z + dn.z; e.w = t_.w + dn.w; }
#define KB_REPLAY(dn, i)                                                       \
    {   int hh = h0 + (i);                                                     \
        if (hh < NHF) zbw[(size_t)hh * NSEQ + id] = zz;                        \
        float4 t_; MV(t_, M1, zz);                                             \
        zz.x = t_.x + dn.x; zz.y = t_.y + dn.y;                                \
        zz.z = t_.z + dn.z; zz.w = t_.w + dn.w; }

// phase-D macros
#define KD_LOAD(gn, yn, i)                                                     \
    {   int kk = k0 + (i); int kcl = (kk < NFRM) ? kk : (NFRM - 1);            \
        size_t ix = ((size_t)b * NFRM + kcl) * NCH + c;                        \
        gn = fmaf(aH, G1[ix], G2[ix]); yn = y4f[ix];                           \
        if (kk >= NFRM) { gn = 0.f; yn = 0.f; } }
#define KD_REPLAY(gn, yn, i)                                                   \
    {   int kk = k0 + (i);                                                     \
        if (kk < NFRM) o[kk] = fmaf(alpha, sv, yn);                            \
        sv = fmaf(aL, sv, gn); }

// ---------------------------------------------------------------------------
// Kernel A: forced-response states at 64-sample granularity. Each (b,h2) cell
// covers samples [128*h2, 128*h2+128) = chunks 2*h2 and 2*h2+1: run 64 steps
// from zero -> store d[2*h2]; reset; 64 more steps -> store d[2*h2+1].
// Blocks [0, KA_EDGE): channel 128 — one cell per lane (wave 0 only).
// Blocks [KA_EDGE, +NT): channels 0..127 — 128 threads, LDS-staged x.
// zs layout: float4 at [h * NSEQ + (c*BS+b)], h in [0, NHF).
// ---------------------------------------------------------------------------
__global__ __launch_bounds__(128, 4) void kA_forced_state(
        const float* __restrict__ wav, const float* __restrict__ B,
        const float* __restrict__ A, float* __restrict__ zs) {
    __shared__ float xs[HALF];
    int blk = blockIdx.x;
    if (blk < KA_EDGE) {
        int item = blk * 64 + threadIdx.x;
        if (threadIdx.x >= 64 || item >= NT) return;
        int b = item / NH;
        int h2 = item - b * NH;
        const float* xg = wav + (size_t)b * TLEN + (size_t)h2 * HALF;
        Coef q = load_coef(B, A, 128);
        float z0 = 0.f, z1 = 0.f, z2 = 0.f, z3 = 0.f;
        #pragma unroll 4
        for (int j = 0; j < CH; ++j) {
            (void)iir_step(q, xg[j], z0, z1, z2, z3);
        }
        ((float4*)zs)[(size_t)(2 * h2) * NSEQ + (128 * BS + b)] =
            make_float4(z0, z1, z2, z3);
        z0 = 0.f; z1 = 0.f; z2 = 0.f; z3 = 0.f;
        #pragma unroll 4
        for (int j = CH; j < HALF; ++j) {
            (void)iir_step(q, xg[j], z0, z1, z2, z3);
        }
        ((float4*)zs)[(size_t)(2 * h2 + 1) * NSEQ + (128 * BS + b)] =
            make_float4(z0, z1, z2, z3);
        return;
    }
    int mblk = blk - KA_EDGE;        // b * NH + h2
    int b = mblk / NH;
    int h2 = mblk - b * NH;
    const float* xg = wav + (size_t)b * TLEN + (size_t)h2 * HALF;
    xs[threadIdx.x] = xg[threadIdx.x];
    __syncthreads();
    int c = threadIdx.x;             // 0..127
    Coef q = load_coef(B, A, c);
    float z0 = 0.f, z1 = 0.f, z2 = 0.f, z3 = 0.f;
    #pragma unroll 8
    for (int j = 0; j < CH; ++j) {
        (void)iir_step(q, xs[j], z0, z1, z2, z3);
    }
    ((float4*)zs)[(size_t)(2 * h2) * NSEQ + (c * BS + b)] =
        make_float4(z0, z1, z2, z3);
    z0 = 0.f; z1 = 0.f; z2 = 0.f; z3 = 0.f;
    #pragma unroll 8
    for (int j = CH; j < HALF; ++j) {
        (void)iir_step(q, xs[j], z0, z1, z2, z3);
    }
    ((float4*)zs)[(size_t)(2 * h2 + 1) * NSEQ + (c * BS + b)] =
        make_float4(z0, z1, z2, z3);
}

// ---------------------------------------------------------------------------
// Kernel B: Kogge-Stone matrix scan over 1000 64-chunk states, one wave per
// (c,b). Lane l owns h in [16l, 16l+16) (1024 >= NHF, padded d=0).
//   z[h] = M64 * z[h-1] + d[h-1], z[0] = 0; M1 = M^64, P = M1^16.
// launch_bounds(256,2): VGPR cap 256 (16 float4 d's + 3 matrices, no spill).
// ---------------------------------------------------------------------------
__global__ __launch_bounds__(256, 2) void kB_scan_par(
        const float* __restrict__ A, float* __restrict__ zs) {
    int id = blockIdx.x * 4 + (threadIdx.x >> 6);   // c * BS + b
    int lane = threadIdx.x & 63;
    if (id >= NSEQ) return;
    int c = id / BS;
    float a1 = A[c * 5 + 1], a2 = A[c * 5 + 2], a3 = A[c * 5 + 3], a4 = A[c * 5 + 4];
    MDECL(M1);
    M100 = -a1; M101 = 1.f; M102 = 0.f; M103 = 0.f;
    M110 = -a2; M111 = 0.f; M112 = 1.f; M113 = 0.f;
    M120 = -a3; M121 = 0.f; M122 = 0.f; M123 = 1.f;
    M130 = -a4; M131 = 0.f; M132 = 0.f; M133 = 0.f;
    for (int s = 0; s < 6; ++s) {        // M^64
        MDECL(T); MMUL(T, M1, M1); MCOPY(M1, T);
    }
    MDECL(P);
    MCOPY(P, M1);
    for (int s = 0; s < 4; ++s) {        // P = M64^16
        MDECL(T); MMUL(T, P, P); MCOPY(P, T);
    }
    const float4* zb = (const float4*)zs;
    float4* zbw = (float4*)zs;
    int h0 = lane * 16;
    float4 d0, d1, d2, d3, d4, d5, d6, d7, d8, d9, d10, d11, d12, d13, d14, d15;
    KB_LOAD(d0, 0);  KB_LOAD(d1, 1);  KB_LOAD(d2, 2);  KB_LOAD(d3, 3);
    KB_LOAD(d4, 4);  KB_LOAD(d5, 5);  KB_LOAD(d6, 6);  KB_LOAD(d7, 7);
    KB_LOAD(d8, 8);  KB_LOAD(d9, 9);  KB_LOAD(d10, 10); KB_LOAD(d11, 11);
    KB_LOAD(d12, 12); KB_LOAD(d13, 13); KB_LOAD(d14, 14); KB_LOAD(d15, 15);
    float4 e = d0;
    KB_FOLD(d1);  KB_FOLD(d2);  KB_FOLD(d3);  KB_FOLD(d4);
    KB_FOLD(d5);  KB_FOLD(d6);  KB_FOLD(d7);  KB_FOLD(d8);
    KB_FOLD(d9);  KB_FOLD(d10); KB_FOLD(d11); KB_FOLD(d12);
    KB_FOLD(d13); KB_FOLD(d14); KB_FOLD(d15);
    for (int s = 0; s < 6; ++s) {
        int off = 1 << s;
        float4 src;
        src.x = __shfl_up(e.x, off, 64);
        src.y = __shfl_up(e.y, off, 64);
        src.z = __shfl_up(e.z, off, 64);
        src.w = __shfl_up(e.w, off, 64);
        if (lane < off) { src.x = 0.f; src.y = 0.f; src.z = 0.f; src.w = 0.f; }
        float4 t_; MV(t_, P, src);
        e.x += t_.x; e.y += t_.y; e.z += t_.z; e.w += t_.w;
        if (s < 5) { MDECL(T); MMUL(T, P, P); MCOPY(P, T); }
    }
    float4 zz;
    zz.x = __shfl_up(e.x, 1, 64);
    zz.y = __shfl_up(e.y, 1, 64);
    zz.z = __shfl_up(e.z, 1, 64);
    zz.w = __shfl_up(e.w, 1, 64);
    if (lane == 0) { zz.x = 0.f; zz.y = 0.f; zz.z = 0.f; zz.w = 0.f; }
    KB_REPLAY(d0, 0);  KB_REPLAY(d1, 1);  KB_REPLAY(d2, 2);  KB_REPLAY(d3, 3);
    KB_REPLAY(d4, 4);  KB_REPLAY(d5, 5);  KB_REPLAY(d6, 6);  KB_REPLAY(d7, 7);
    KB_REPLAY(d8, 8);  KB_REPLAY(d9, 9);  KB_REPLAY(d10, 10); KB_REPLAY(d11, 11);
    KB_REPLAY(d12, 12); KB_REPLAY(d13, 13); KB_REPLAY(d14, 14); KB_REPLAY(d15, 15);
}

// ---------------------------------------------------------------------------
// Kernel C: 128-sample tiles with 64-step full warm-up from the EXACT state
// at sample 128r-64 (zs index 2r-1). beta^64 truncation (same class as r8).
// Tile r: frame k = r>>1, half = r&1; first-half emits y4f+G1, second G2.
// Blocks [0, KC_EDGE): channel-128 path, one (b,r) cell per thread.
// Blocks [KC_EDGE, +KC_MAIN): pair-channel main, wave w -> tile blk*4+w;
// lane t runs packed chains {2t,2t+1}; shfl consumed one step late.
// ---------------------------------------------------------------------------
__global__ __launch_bounds__(256, 8) void kC_main(
        const float* __restrict__ wav, const float* __restrict__ B,
        const float* __restrict__ A, const float* __restrict__ zs,
        float* __restrict__ G1, float* __restrict__ G2,
        float* __restrict__ y4f, float beta, float alpha) {
    __shared__ float4 xs4[4][48];    // per-wave: 16 warm + 32 main groups
    int blk = blockIdx.x;
    const f2 beta2 = mk2(beta, beta);
    const f2 alpha2 = mk2(alpha, alpha);

    if (blk < KC_EDGE) {
        // ---- edge: channel 128, one (b,r) per thread ----
        int cell = blk * 256 + threadIdx.x;
        if (cell >= NT) return;
        int b = cell / NH;
        int r = cell - b * NH;
        int k = r >> 1, half = r & 1;
        C2 q = load_coef2(B, A, 127, 128);
        f2 z0 = mk2(0.f, 0.f), z1 = z0, z2 = z0, z3 = z0, u = z0;
        const float* xg;
        if (r > 0) {
            float4 vx = ((const float4*)zs)[(size_t)(2 * r - 1) * NSEQ + (127 * BS + b)];
            float4 vy = ((const float4*)zs)[(size_t)(2 * r - 1) * NSEQ + (128 * BS + b)];
            z0 = mk2(vx.x, vy.x); z1 = mk2(vx.y, vy.y);
            z2 = mk2(vx.z, vy.z); z3 = mk2(vx.w, vy.w);
            xg = wav + (size_t)b * TLEN + ((size_t)r * HALF - CH);
            #pragma unroll 2
            for (int j = 0; j < CH; ++j) WSTEP(xg[j]);
            xg += CH;
        } else {
            xg = wav + (size_t)b * TLEN;
        }
        float g4 = 0.f, yfirst = 0.f;
        #pragma unroll 2
        for (int j = 0; j < HALF; ++j) {
            f2 y_ = iir2_step(q, xg[j], z0, z1, z2, z3);
            u = fma2(beta2, u, sig2(y_));
            float y4 = fmaxf(u.y - u.x, 0.0f);   // ch128 - ch127
            if (j == 0) yfirst = y4;
            g4 = fmaf(alpha, g4, y4);
        }
        size_t idx = ((size_t)b * NFRM + k) * NCH + 128;
        if (half == 0) { G1[idx] = g4; y4f[idx] = yfirst; }
        else           { G2[idx] = g4; }
        return;
    }

    // ---- main: wave w handles tile (blk-KC_EDGE)*4 + w ----
    int wave = threadIdx.x >> 6;
    int lane = threadIdx.x & 63;
    int tile = (blk - KC_EDGE) * 4 + wave;   // < NT
    int b = tile / NH;
    int r = tile - b * NH;
    int k = r >> 1, half = r & 1;
    int n4 = (r > 0) ? 48 : 32;
    const float* xg = wav + (size_t)b * TLEN +
                      ((r > 0) ? ((size_t)r * HALF - CH) : (size_t)0);
    float4* seg = &xs4[wave][0];
    if (lane < n4) seg[lane] = ((const float4*)xg)[lane];
    __syncthreads();

    int t = lane;
    int cA = 2 * t, cB2 = 2 * t + 1;
    C2 q = load_coef2(B, A, cA, cB2);
    f2 z0 = mk2(0.f, 0.f), z1 = z0, z2 = z0, z3 = z0, u = z0;
    int gbase = 0;
    if (r > 0) {
        float4 vx = ((const float4*)zs)[(size_t)(2 * r - 1) * NSEQ + (cA * BS + b)];
        float4 vy = ((const float4*)zs)[(size_t)(2 * r - 1) * NSEQ + (cB2 * BS + b)];
        z0 = mk2(vx.x, vy.x); z1 = mk2(vx.y, vy.y);
        z2 = mk2(vx.z, vy.z); z3 = mk2(vx.w, vy.w);
        for (int g = 0; g < CH / 4; ++g) {       // 64 full warm steps
            float4 xq = seg[g];
            WSTEP(xq.x); WSTEP(xq.y); WSTEP(xq.z); WSTEP(xq.w);
        }
        gbase = CH / 4;                          // 16
    }
    f2 g2;
    float fo, fe, pend_un, pend_ub;
    {   // first main group: peel j=0 and j=1
        float4 xq = seg[gbase];
        f2 y_ = iir2_step(q, xq.x, z0, z1, z2, z3);
        u = fma2(beta2, u, sig2(y_));
        float un_ = __shfl_down(u.x, 1, 64);
        float y4o_ = fmaxf(u.y - u.x, 0.0f);
        fo = y4o_;
        g2 = mk2(y4o_, 0.0f);
        pend_un = un_; pend_ub = u.y;
        y_ = iir2_step(q, xq.y, z0, z1, z2, z3);
        u = fma2(beta2, u, sig2(y_));
        un_ = __shfl_down(u.x, 1, 64);
        y4o_ = fmaxf(u.y - u.x, 0.0f);
        float y4e_ = fmaxf(pend_un - pend_ub, 0.0f);
        fe = y4e_;
        g2 = fma2(alpha2, g2, mk2(y4o_, y4e_));
        pend_un = un_; pend_ub = u.y;
        MSTEP(xq.z); MSTEP(xq.w);
    }
    for (int g = gbase + 1; g < gbase + HALF / 4; ++g) {
        float4 xq = seg[g];
        MSTEP(xq.x); MSTEP(xq.y); MSTEP(xq.z); MSTEP(xq.w);
    }
    float y4e_last = fmaxf(pend_un - pend_ub, 0.0f);
    float go = g2.x;
    float ge = fmaf(alpha, g2.y, y4e_last);
    size_t base = ((size_t)b * NFRM + k) * NCH;
    if (half == 0) {
        G1[base + cB2] = go;
        y4f[base + cB2] = fo;
        if (t < 63) {
            G1[base + cB2 + 1] = ge;
            y4f[base + cB2 + 1] = fe;
        }
    } else {
        G2[base + cB2] = go;
        if (t < 63) G2[base + cB2 + 1] = ge;
    }
}

// ---------------------------------------------------------------------------
// Kernel D (round-8 proven): parallel alpha-scan, one wave per (b,c).
//   o[k] = alpha*s + y4f[k];  s' = aL*s + (aH*G1[k] + G2[k]).
// ---------------------------------------------------------------------------
__global__ __launch_bounds__(256) void kD_scan_par(
        const float* __restrict__ G1, const float* __restrict__ G2,
        const float* __restrict__ y4f, float* __restrict__ out,
        float alpha, float aL, float aH) {
    int id = blockIdx.x * 4 + (threadIdx.x >> 6);   // b * NCH + c
    int lane = threadIdx.x & 63;
    if (id >= NSEQ) return;
    int b = id / NCH;
    int c = id - b * NCH;
    float* o = out + (size_t)id * NFRM;
    int k0 = lane * 4;
    if (c == 0) {
        #pragma unroll
        for (int i = 0; i < 4; ++i) {
            int kk = k0 + i;
            if (kk < NFRM) o[kk] = 0.0f;
        }
        return;
    }
    float g0, g1, g2v, g3, y0, y1, y2v, y3;
    KD_LOAD(g0, y0, 0); KD_LOAD(g1, y1, 1); KD_LOAD(g2v, y2v, 2); KD_LOAD(g3, y3, 3);
    float e = g0;
    e = fmaf(aL, e, g1);
    e = fmaf(aL, e, g2v);
    e = fmaf(aL, e, g3);
    float aL2 = aL * aL;
    float f = aL2 * aL2;                 // aL^4
    for (int s = 0; s < 6; ++s) {
        int off = 1 << s;
        float src = __shfl_up(e, off, 64);
        if (lane < off) src = 0.f;
        e = fmaf(f, src, e);
        f = f * f;
    }
    float sv = __shfl_up(e, 1, 64);
    if (lane == 0) sv = 0.f;
    KD_REPLAY(g0, y0, 0); KD_REPLAY(g1, y1, 1);
    KD_REPLAY(g2v, y2v, 2); KD_REPLAY(g3, y3, 3);
}

// ---------------------------------------------------------------------------
extern "C" void kernel_launch(void* const* d_in, const int* in_sizes, int n_in,
                              void* d_out, int out_size, void* d_ws, size_t ws_size,
                              hipStream_t stream) {
    const float* wav = (const float*)d_in[0];   // (BS, TLEN)
    const float* Bc  = (const float*)d_in[1];   // (NCH, 5)
    const float* Ac  = (const float*)d_in[2];   // (NCH, 5)
    float* out = (float*)d_out;                 // (BS, NCH, NFRM)

    // workspace: zs (NHF*NSEQ float4 = 16.5 MB) | G1 | G2 | y4f (1.03 MB each)
    float* zs  = (float*)d_ws;
    float* G1  = zs + (size_t)NHF * NSEQ * 4;
    float* G2  = G1 + (size_t)NBK * NCH;
    float* y4f = G2 + (size_t)NBK * NCH;

    const float alpha  = (float)exp(-1.0 / 128.0);
    const float beta   = (float)exp(-1.0 / 8.0);
    const float alphaL = (float)exp(-256.0 / 128.0);   // alpha^256 (frame step)
    const float alphaH = (float)exp(-128.0 / 128.0);   // alpha^128

    kA_forced_state<<<KA_EDGE + NT, 128, 0, stream>>>(wav, Bc, Ac, zs);
    kB_scan_par<<<(NSEQ + 3) / 4, 256, 0, stream>>>(Ac, zs);
    kC_main<<<KC_EDGE + KC_MAIN, 256, 0, stream>>>(wav, Bc, Ac, zs, G1, G2, y4f, beta, alpha);
    kD_scan_par<<<(NSEQ + 3) / 4, 256, 0, stream>>>(G1, G2, y4f, out, alpha, alphaL, alphaH);
}